// Round 3
// baseline (2341.389 us; speedup 1.0000x reference)
//
#include <hip/hip_runtime.h>
#include <math.h>

#define NSAMP 262144
#define TM 16
#define SROW 20   // padded LDS row stride (floats): keeps float4 aligned, breaks worst bank conflicts

__device__ __forceinline__ float fast_tanh(float v) {
  // tanh(v) = 1 - 2/(exp(2v)+1); saturates correctly at +-inf, no NaN
  float e = __expf(2.0f * v);
  return 1.0f - 2.0f / (e + 1.0f);
}

// ---------------------------------------------------------------------------
// K1: fused MLP. One block = 16 samples. Activations transposed in LDS.
//   A: 512 x SROW floats (40 KB)   B: 256 x SROW floats (20 KB)
// ---------------------------------------------------------------------------
__global__ __launch_bounds__(256) void k1_mlp(
    const float* __restrict__ x,
    const float* __restrict__ W0, const float* __restrict__ b0,
    const float* __restrict__ W1, const float* __restrict__ b1,
    const float* __restrict__ W2, const float* __restrict__ b2,
    const float* __restrict__ W3, const float* __restrict__ b3,
    const float* __restrict__ E0, const float* __restrict__ eb0,
    const float* __restrict__ E1, const float* __restrict__ eb1,
    const float* __restrict__ E2, const float* __restrict__ eb2,
    float* __restrict__ zg, float* __restrict__ gamma)
{
  __shared__ float A[512 * SROW];
  __shared__ float B[256 * SROW];
  const int tid = threadIdx.x;
  const int blk = blockIdx.x;

  // ---- stage x tile -> B as xT[k][s] ----
  {
    const float* xb = x + (size_t)blk * (TM * 128);
    for (int v = tid; v < 512; v += 256) {
      const float4 t = *(const float4*)(xb + v * 4);
      const int s = v >> 5;          // (v*4)/128
      const int k = (v & 31) * 4;
      B[(k + 0) * SROW + s] = t.x;
      B[(k + 1) * SROW + s] = t.y;
      B[(k + 2) * SROW + s] = t.z;
      B[(k + 3) * SROW + s] = t.w;
    }
  }
  __syncthreads();

  // ---- L1: 128 -> 512 tanh.  thread: 4 outputs (og+128j) x 8 samples ----
  {
    const int og = tid & 127;
    const int sg = tid >> 7;
    float acc[4][8];
#pragma unroll
    for (int j = 0; j < 4; ++j) {
      const float b = b0[og + 128 * j];
#pragma unroll
      for (int i = 0; i < 8; ++i) acc[j][i] = b;
    }
    const float* bx = &B[sg * 8];
#pragma unroll 4
    for (int k = 0; k < 128; ++k) {
      const float4 xa  = *(const float4*)(bx + k * SROW);
      const float4 xb4 = *(const float4*)(bx + k * SROW + 4);
      const float xs[8] = {xa.x, xa.y, xa.z, xa.w, xb4.x, xb4.y, xb4.z, xb4.w};
      const float* wr = W0 + k * 512 + og;
      const float w[4] = {wr[0], wr[128], wr[256], wr[384]};
#pragma unroll
      for (int j = 0; j < 4; ++j)
#pragma unroll
        for (int i = 0; i < 8; ++i)
          acc[j][i] = fmaf(w[j], xs[i], acc[j][i]);
    }
#pragma unroll
    for (int j = 0; j < 4; ++j)
#pragma unroll
      for (int i = 0; i < 8; ++i)
        A[(og + 128 * j) * SROW + sg * 8 + i] = fast_tanh(acc[j][i]);
  }
  __syncthreads();

  // ---- L2: 512 -> 256 tanh.  thread: 2 outputs x 8 samples ----
  {
    const int og = tid & 127;
    const int sg = tid >> 7;
    float acc[2][8];
#pragma unroll
    for (int j = 0; j < 2; ++j) {
      const float b = b1[og + 128 * j];
#pragma unroll
      for (int i = 0; i < 8; ++i) acc[j][i] = b;
    }
    const float* ax = &A[sg * 8];
#pragma unroll 4
    for (int k = 0; k < 512; ++k) {
      const float4 xa  = *(const float4*)(ax + k * SROW);
      const float4 xb4 = *(const float4*)(ax + k * SROW + 4);
      const float xs[8] = {xa.x, xa.y, xa.z, xa.w, xb4.x, xb4.y, xb4.z, xb4.w};
      const float* wr = W1 + k * 256 + og;
      const float w0v = wr[0], w1v = wr[128];
#pragma unroll
      for (int i = 0; i < 8; ++i) {
        acc[0][i] = fmaf(w0v, xs[i], acc[0][i]);
        acc[1][i] = fmaf(w1v, xs[i], acc[1][i]);
      }
    }
#pragma unroll
    for (int j = 0; j < 2; ++j)
#pragma unroll
      for (int i = 0; i < 8; ++i)
        B[(og + 128 * j) * SROW + sg * 8 + i] = fast_tanh(acc[j][i]);
  }
  __syncthreads();

  // ---- L3: 256 -> 64 tanh.  thread: 1 output x 4 samples ----
  {
    const int o = tid & 63;
    const int sg = tid >> 6;      // 0..3 -> samples sg*4..+3
    float acc[4];
    const float b = b2[o];
#pragma unroll
    for (int i = 0; i < 4; ++i) acc[i] = b;
#pragma unroll 4
    for (int k = 0; k < 256; ++k) {
      const float4 xa = *(const float4*)(&B[k * SROW + sg * 4]);
      const float w = W2[k * 64 + o];
      acc[0] = fmaf(w, xa.x, acc[0]);
      acc[1] = fmaf(w, xa.y, acc[1]);
      acc[2] = fmaf(w, xa.z, acc[2]);
      acc[3] = fmaf(w, xa.w, acc[3]);
    }
#pragma unroll
    for (int i = 0; i < 4; ++i)
      A[o * SROW + sg * 4 + i] = fast_tanh(acc[i]);
  }
  __syncthreads();

  // ---- L4: 64 -> 8 linear (z). 128 threads: tid = s*8+d ----
  if (tid < 128) {
    const int d = tid & 7;
    const int s = tid >> 3;
    float acc = b3[d];
#pragma unroll 8
    for (int k = 0; k < 64; ++k)
      acc = fmaf(A[k * SROW + s], W3[k * 8 + d], acc);
    B[d * SROW + s] = acc;                     // zT
    zg[(size_t)blk * 128 + tid] = acc;         // z[n][d], n = blk*16+s
  }
  __syncthreads();

  // ---- E0: 8 -> 128 tanh.  thread: 1 output x 8 samples ----
  {
    const int o = tid & 127;
    const int sg = tid >> 7;
    float acc[8];
    const float b = eb0[o];
#pragma unroll
    for (int i = 0; i < 8; ++i) acc[i] = b;
#pragma unroll
    for (int k = 0; k < 8; ++k) {
      const float4 xa  = *(const float4*)(&B[k * SROW + sg * 8]);
      const float4 xb4 = *(const float4*)(&B[k * SROW + sg * 8 + 4]);
      const float xs[8] = {xa.x, xa.y, xa.z, xa.w, xb4.x, xb4.y, xb4.z, xb4.w};
      const float w = E0[k * 128 + o];
#pragma unroll
      for (int i = 0; i < 8; ++i) acc[i] = fmaf(w, xs[i], acc[i]);
    }
#pragma unroll
    for (int i = 0; i < 8; ++i)
      A[o * SROW + sg * 8 + i] = fast_tanh(acc[i]);
  }
  __syncthreads();

  // ---- E1: 128 -> 64 tanh.  thread: 1 output x 4 samples ----
  {
    const int o = tid & 63;
    const int sg = tid >> 6;
    float acc[4];
    const float b = eb1[o];
#pragma unroll
    for (int i = 0; i < 4; ++i) acc[i] = b;
#pragma unroll 4
    for (int k = 0; k < 128; ++k) {
      const float4 xa = *(const float4*)(&A[k * SROW + sg * 4]);
      const float w = E1[k * 64 + o];
      acc[0] = fmaf(w, xa.x, acc[0]);
      acc[1] = fmaf(w, xa.y, acc[1]);
      acc[2] = fmaf(w, xa.z, acc[2]);
      acc[3] = fmaf(w, xa.w, acc[3]);
    }
#pragma unroll
    for (int i = 0; i < 4; ++i)
      B[o * SROW + sg * 4 + i] = fast_tanh(acc[i]);
  }
  __syncthreads();

  // ---- E2: 64 -> 16 + softmax.  thread = (sample s, component kk) ----
  {
    const int kk = tid & 15;
    const int s = tid >> 4;
    float acc = eb2[kk];
#pragma unroll 8
    for (int k = 0; k < 64; ++k)
      acc = fmaf(B[k * SROW + s], E2[k * 16 + kk], acc);
    float m = acc;
#pragma unroll
    for (int off = 8; off > 0; off >>= 1)
      m = fmaxf(m, __shfl_xor(m, off, 16));
    const float e = __expf(acc - m);
    float sum = e;
#pragma unroll
    for (int off = 8; off > 0; off >>= 1)
      sum += __shfl_xor(sum, off, 16);
    gamma[(size_t)blk * 256 + tid] = e / sum;   // gamma[n][kk]
  }
}

// ---------------------------------------------------------------------------
// K2: GMM moment accumulation. thread = (k = tid&15, 64-sample chunk).
// stats[k*45 + p]: p<36 = sum gamma*z_l*z_m (l<=m); 36..43 = sum gamma*z_l; 44 = sum gamma
// ---------------------------------------------------------------------------
__global__ __launch_bounds__(256) void k2_stats(
    const float* __restrict__ zg, const float* __restrict__ gamma,
    float* __restrict__ stats)
{
  const int tid = threadIdx.x;
  const int k = tid & 15;
  const int chunk = blockIdx.x * 16 + (tid >> 4);
  const int s0 = chunk * 64;
  float m2[36], m1[8], gs = 0.f;
#pragma unroll
  for (int i = 0; i < 36; ++i) m2[i] = 0.f;
#pragma unroll
  for (int i = 0; i < 8; ++i) m1[i] = 0.f;

  for (int i = 0; i < 64; ++i) {
    const int n = s0 + i;
    const float4 za = *(const float4*)(zg + (size_t)n * 8);
    const float4 zb = *(const float4*)(zg + (size_t)n * 8 + 4);
    const float zv[8] = {za.x, za.y, za.z, za.w, zb.x, zb.y, zb.z, zb.w};
    const float g = gamma[(size_t)n * 16 + k];
    gs += g;
    float t[8];
#pragma unroll
    for (int l = 0; l < 8; ++l) { t[l] = g * zv[l]; m1[l] += t[l]; }
    int p = 0;
#pragma unroll
    for (int l = 0; l < 8; ++l)
#pragma unroll
      for (int m = l; m < 8; ++m) {
        m2[p] = fmaf(t[l], zv[m], m2[p]);
        ++p;
      }
  }

  // reduce the 4 quarter-wave chunk-groups, then one atomic set per wave
#pragma unroll
  for (int i = 0; i < 36; ++i) {
    m2[i] += __shfl_xor(m2[i], 16);
    m2[i] += __shfl_xor(m2[i], 32);
  }
#pragma unroll
  for (int i = 0; i < 8; ++i) {
    m1[i] += __shfl_xor(m1[i], 16);
    m1[i] += __shfl_xor(m1[i], 32);
  }
  gs += __shfl_xor(gs, 16);
  gs += __shfl_xor(gs, 32);

  if ((tid & 48) == 0) {
    float* sk = stats + k * 45;
#pragma unroll
    for (int i = 0; i < 36; ++i) atomicAdd(&sk[i], m2[i]);
#pragma unroll
    for (int i = 0; i < 8; ++i) atomicAdd(&sk[36 + i], m1[i]);
    atomicAdd(&sk[44], gs);
  }
}

// ---------------------------------------------------------------------------
// K3: per-component finalize: mu, sigma, cholesky, Sigma^-1, fold into
//   logit_k(z) = cnst + c.z - 0.5 z^T A z   coefficients (48 floats per k)
// ---------------------------------------------------------------------------
__global__ void k3_finalize(const float* __restrict__ stats, float* __restrict__ coef)
{
  const int k = threadIdx.x;
  if (k >= 16) return;
  const float* sk = stats + k * 45;
  const float gs = sk[44];
  float mu[8];
#pragma unroll
  for (int l = 0; l < 8; ++l) mu[l] = sk[36 + l] / gs;

  float S[8][8];
  {
    int p = 0;
    for (int l = 0; l < 8; ++l)
      for (int m = l; m < 8; ++m) {
        const float v = sk[p++] / gs - mu[l] * mu[m];
        S[l][m] = v; S[m][l] = v;
      }
  }
  for (int l = 0; l < 8; ++l) S[l][l] += 1e-6f;

  float L[8][8];
  for (int i = 0; i < 8; ++i)
    for (int j = 0; j <= i; ++j) {
      float s = S[i][j];
      for (int t = 0; t < j; ++t) s -= L[i][t] * L[j][t];
      if (i == j) L[i][i] = sqrtf(s);
      else        L[i][j] = s / L[j][j];
    }
  float logdet = 0.f;
  for (int i = 0; i < 8; ++i) logdet += logf(L[i][i]);
  logdet *= 2.f;

  float U[8][8];   // U = L^-1 (lower)
  for (int j = 0; j < 8; ++j) {
    U[j][j] = 1.f / L[j][j];
    for (int i = j + 1; i < 8; ++i) {
      float s = 0.f;
      for (int t = j; t < i; ++t) s += L[i][t] * U[t][j];
      U[i][j] = -s / L[i][i];
    }
  }
  float Amat[8][8];   // Sigma^-1 = U^T U
  for (int l = 0; l < 8; ++l)
    for (int m = l; m < 8; ++m) {
      float s = 0.f;
      for (int i = m; i < 8; ++i) s += U[i][l] * U[i][m];
      Amat[l][m] = s; Amat[m][l] = s;
    }
  float c[8];
  for (int l = 0; l < 8; ++l) {
    float s = 0.f;
    for (int m = 0; m < 8; ++m) s += Amat[l][m] * mu[m];
    c[l] = s;
  }
  float muAmu = 0.f;
  for (int l = 0; l < 8; ++l) muAmu += c[l] * mu[l];

  const float LOG2PI = 1.8378770664093453f;
  const float cnst = logf(gs) - logf((float)NSAMP)
                   - 0.5f * (8.f * LOG2PI + logdet + muAmu);

  float* ck = coef + k * 48;
  {
    int p = 0;
    for (int l = 0; l < 8; ++l)
      for (int m = l; m < 8; ++m) {
        ck[p] = (l == m) ? (-0.5f * Amat[l][l]) : (-Amat[l][m]);
        ++p;
      }
  }
  for (int l = 0; l < 8; ++l) ck[36 + l] = c[l];
  ck[44] = cnst;
  ck[45] = 0.f; ck[46] = 0.f; ck[47] = 0.f;
}

// ---------------------------------------------------------------------------
// K4: per-sample energy: shared z-products across 16 components + online LSE
// ---------------------------------------------------------------------------
__global__ __launch_bounds__(256) void k4_energy(
    const float* __restrict__ zg, const float* __restrict__ coef,
    float* __restrict__ prob)
{
  __shared__ float C[16 * 48];
  for (int i = threadIdx.x; i < 16 * 48; i += 256) C[i] = coef[i];
  __syncthreads();

  const int n = blockIdx.x * 256 + threadIdx.x;
  const float4 za = *(const float4*)(zg + (size_t)n * 8);
  const float4 zb = *(const float4*)(zg + (size_t)n * 8 + 4);
  const float z[8] = {za.x, za.y, za.z, za.w, zb.x, zb.y, zb.z, zb.w};

  float pr[36];
  {
    int p = 0;
#pragma unroll
    for (int l = 0; l < 8; ++l)
#pragma unroll
      for (int m = l; m < 8; ++m) pr[p++] = z[l] * z[m];
  }

  float mx = -1e30f, sm = 0.f;
#pragma unroll
  for (int k = 0; k < 16; ++k) {
    const float4* c4 = (const float4*)&C[k * 48];
    float acc = C[k * 48 + 44];
#pragma unroll
    for (int q = 0; q < 9; ++q) {
      const float4 t = c4[q];
      acc = fmaf(t.x, pr[q * 4 + 0], acc);
      acc = fmaf(t.y, pr[q * 4 + 1], acc);
      acc = fmaf(t.z, pr[q * 4 + 2], acc);
      acc = fmaf(t.w, pr[q * 4 + 3], acc);
    }
    {
      const float4 t = c4[9];
      acc = fmaf(t.x, z[0], acc); acc = fmaf(t.y, z[1], acc);
      acc = fmaf(t.z, z[2], acc); acc = fmaf(t.w, z[3], acc);
    }
    {
      const float4 t = c4[10];
      acc = fmaf(t.x, z[4], acc); acc = fmaf(t.y, z[5], acc);
      acc = fmaf(t.z, z[6], acc); acc = fmaf(t.w, z[7], acc);
    }
    const float nm = fmaxf(mx, acc);
    sm = sm * __expf(mx - nm) + __expf(acc - nm);
    mx = nm;
  }
  prob[n] = -(mx + __logf(sm));
}

// ---------------------------------------------------------------------------
extern "C" void kernel_launch(void* const* d_in, const int* in_sizes, int n_in,
                              void* d_out, int out_size, void* d_ws, size_t ws_size,
                              hipStream_t stream)
{
  const float* x   = (const float*)d_in[0];
  const float* W0  = (const float*)d_in[1];
  const float* b0  = (const float*)d_in[2];
  const float* W1  = (const float*)d_in[3];
  const float* b1  = (const float*)d_in[4];
  const float* W2  = (const float*)d_in[5];
  const float* b2  = (const float*)d_in[6];
  const float* W3  = (const float*)d_in[7];
  const float* b3  = (const float*)d_in[8];
  const float* E0  = (const float*)d_in[9];
  const float* eb0 = (const float*)d_in[10];
  const float* E1  = (const float*)d_in[11];
  const float* eb1 = (const float*)d_in[12];
  const float* E2  = (const float*)d_in[13];
  const float* eb2 = (const float*)d_in[14];

  float* out  = (float*)d_out;
  float* prob = out;              // [N]
  float* zg   = out + NSAMP;      // [N][8]

  float* ws    = (float*)d_ws;
  float* gamma = ws;                          // [N][16]
  float* stats = ws + (size_t)NSAMP * 16;     // 16*45 floats
  float* coef  = stats + 768;                 // 16*48 floats

  hipMemsetAsync(stats, 0, 16 * 45 * sizeof(float), stream);

  k1_mlp<<<NSAMP / TM, 256, 0, stream>>>(x, W0, b0, W1, b1, W2, b2, W3, b3,
                                         E0, eb0, E1, eb1, E2, eb2, zg, gamma);
  k2_stats<<<256, 256, 0, stream>>>(zg, gamma, stats);
  k3_finalize<<<1, 64, 0, stream>>>(stats, coef);
  k4_energy<<<NSAMP / 256, 256, 0, stream>>>(zg, coef, prob);
}

// Round 4
// 739.967 us; speedup vs baseline: 3.1642x; 3.1642x over previous
//
#include <hip/hip_runtime.h>
#include <math.h>

#define NSAMP 262144
#define TMS 32   // samples per block in k1

typedef __bf16  bf16x8 __attribute__((ext_vector_type(8)));
typedef float   f32x4  __attribute__((ext_vector_type(4)));
typedef unsigned short u16x8 __attribute__((ext_vector_type(8)));
typedef unsigned short u16x4 __attribute__((ext_vector_type(4)));

__device__ __forceinline__ float fast_tanh(float v) {
  float e = __expf(2.0f * v);
  return 1.0f - 2.0f / (e + 1.0f);
}
__device__ __forceinline__ unsigned short f2bf(float f) {
  unsigned u = __float_as_uint(f);
  unsigned r = (u + 0x7FFFu + ((u >> 16) & 1u)) >> 16;   // RNE
  return (unsigned short)r;
}
__device__ __forceinline__ float bf2f(unsigned short b) {
  return __uint_as_float(((unsigned)b) << 16);
}

// ---------------------------------------------------------------------------
// K0: pack W0,W1,W2,E1 (fp32 [K][N]) into bf16 MFMA B-fragments.
// frag f covers (nt,ks); lane l holds W[k = ks*32+(l>>4)*8+i][n = nt*16+(l&15)]
// frag ids: L1 [0,128) NKS=4 N=512 | L2 [128,384) NKS=16 N=256
//           L3 [384,416) NKS=8 N=64 | E1 [416,432) NKS=4 N=64
// ---------------------------------------------------------------------------
__global__ void k0_pack(const float* __restrict__ W0, const float* __restrict__ W1,
                        const float* __restrict__ W2, const float* __restrict__ E1w,
                        unsigned short* __restrict__ wpack)
{
  const int f = blockIdx.x;
  const int lane = threadIdx.x;
  const float* W; int NKS, N, local;
  if (f < 128)      { W = W0;  NKS = 4;  N = 512; local = f; }
  else if (f < 384) { W = W1;  NKS = 16; N = 256; local = f - 128; }
  else if (f < 416) { W = W2;  NKS = 8;  N = 64;  local = f - 384; }
  else              { W = E1w; NKS = 4;  N = 64;  local = f - 416; }
  const int nt = local / NKS, ks = local % NKS;
  const int n = nt * 16 + (lane & 15);
  const int kbase = ks * 32 + (lane >> 4) * 8;
  unsigned short* out = wpack + ((size_t)f * 64 + lane) * 8;
#pragma unroll
  for (int i = 0; i < 8; ++i)
    out[i] = f2bf(W[(size_t)(kbase + i) * N + n]);
}

// ---------------------------------------------------------------------------
// MFMA tanh layer: in/out are LDS bf16 [32][K or N] with byte-swizzle
// byte ^= ((row&7)<<4). Wave wv handles n-tiles [wv*NTPW, wv*NTPW+NTPW).
// ---------------------------------------------------------------------------
template<int NKS, int NTPW>
__device__ __forceinline__ void mfma_layer(
    const char* __restrict__ in, int inRowB, char* __restrict__ outb, int outRowB,
    const unsigned short* __restrict__ wp, const float* __restrict__ bias,
    int lane, int wv)
{
  const int l15 = lane & 15, lg = lane >> 4;
  const int sw = (l15 & 7) << 4;   // same for st0 (l15) and st1 (16+l15)
  for (int t = 0; t < NTPW; ++t) {
    const int nt = wv * NTPW + t;
    const float bv = bias[nt * 16 + l15];
    f32x4 acc0 = {bv, bv, bv, bv}, acc1 = {bv, bv, bv, bv};
#pragma unroll
    for (int kc = 0; kc < NKS; kc += 4) {
      bf16x8 a0[4], a1[4], b[4];
#pragma unroll
      for (int q = 0; q < 4; ++q) {
        const int colb = (kc + q) * 64 + lg * 16;
        a0[q] = *(const bf16x8*)(in + l15 * inRowB + (colb ^ sw));
        a1[q] = *(const bf16x8*)(in + (16 + l15) * inRowB + (colb ^ sw));
        b[q]  = *(const bf16x8*)(wp + ((size_t)(nt * NKS + kc + q) * 64 + lane) * 8);
      }
#pragma unroll
      for (int q = 0; q < 4; ++q) {
        acc0 = __builtin_amdgcn_mfma_f32_16x16x32_bf16(a0[q], b[q], acc0, 0, 0, 0);
        acc1 = __builtin_amdgcn_mfma_f32_16x16x32_bf16(a1[q], b[q], acc1, 0, 0, 0);
      }
    }
    // D: sample m=(lane>>4)*4+r (+16 for st1), n = nt*16+l15
#pragma unroll
    for (int r = 0; r < 4; ++r) {
      const int nb = (nt * 16 + l15) * 2;
      const int m0 = lg * 4 + r;
      *(unsigned short*)(outb + m0 * outRowB + (nb ^ ((m0 & 7) << 4))) =
          f2bf(fast_tanh(acc0[r]));
      const int m1 = m0 + 16;
      *(unsigned short*)(outb + m1 * outRowB + (nb ^ ((m1 & 7) << 4))) =
          f2bf(fast_tanh(acc1[r]));
    }
  }
}

// ---------------------------------------------------------------------------
// K1: fused MLP, MFMA for L1/L2/L3/E1, VALU for L4/E0/E2+softmax.
// LDS: B region 16 KB (x -> h2 -> z -> e1), A region 32 KB (h1 -> h3 -> e0)
// ---------------------------------------------------------------------------
__global__ __launch_bounds__(256, 3) void k1_mfma(
    const float* __restrict__ x, const unsigned short* __restrict__ wpack,
    const float* __restrict__ b0, const float* __restrict__ b1,
    const float* __restrict__ b2,
    const float* __restrict__ W3, const float* __restrict__ b3,
    const float* __restrict__ E0w, const float* __restrict__ eb0,
    const float* __restrict__ eb1,
    const float* __restrict__ E2w, const float* __restrict__ eb2,
    float* __restrict__ zg, float* __restrict__ gamma)
{
  __shared__ char sm[49152];
  char* B = sm;            // 16 KB
  char* A = sm + 16384;    // 32 KB
  const int tid = threadIdx.x;
  const int lane = tid & 63, wv = tid >> 6;
  const int blk = blockIdx.x;

  // ---- stage x tile -> B: bf16 [32][128], rows 256B, swizzled ----
  {
    const float* xb = x + (size_t)blk * (TMS * 128);
#pragma unroll
    for (int p = 0; p < 4; ++p) {
      const int v = tid + p * 256;
      const float4 t = *(const float4*)(xb + v * 4);
      const int s = v >> 5, k0 = (v & 31) * 4;
      u16x4 h = { f2bf(t.x), f2bf(t.y), f2bf(t.z), f2bf(t.w) };
      *(u16x4*)(B + s * 256 + ((k0 * 2) ^ ((s & 7) << 4))) = h;
    }
  }
  __syncthreads();

  // L1: 128 -> 512 tanh
  mfma_layer<4, 8>(B, 256, A, 1024, wpack, b0, lane, wv);
  __syncthreads();
  // L2: 512 -> 256 tanh
  mfma_layer<16, 4>(A, 1024, B, 512, wpack + (size_t)128 * 512, b1, lane, wv);
  __syncthreads();
  // L3: 256 -> 64 tanh
  mfma_layer<8, 1>(B, 512, A, 128, wpack + (size_t)384 * 512, b2, lane, wv);
  __syncthreads();

  // L4 (VALU): h3[32][64] bf16 (A) -> z fp32 [32][8] (B) + zg global
  {
    const int s = tid >> 3, d = tid & 7;
    const int swz = (s & 7) << 4;
    float acc = b3[d];
#pragma unroll
    for (int c = 0; c < 8; ++c) {
      u16x8 hv = *(const u16x8*)(A + s * 128 + ((c * 16) ^ swz));
#pragma unroll
      for (int i = 0; i < 8; ++i)
        acc = fmaf(bf2f(hv[i]), W3[(c * 8 + i) * 8 + d], acc);
    }
    *(float*)(B + (s * 8 + d) * 4) = acc;
    zg[(size_t)blk * 256 + tid] = acc;
  }
  __syncthreads();

  // E0 (VALU): z (B fp32) -> e0 bf16 [32][128] (A), rows 256B swizzled
  {
    const int o = tid & 127, half = tid >> 7;
    float w[8];
#pragma unroll
    for (int k = 0; k < 8; ++k) w[k] = E0w[k * 128 + o];
    const float bias = eb0[o];
#pragma unroll
    for (int j = 0; j < 16; ++j) {
      const int s = half * 16 + j;
      const float* zr = (const float*)(B + s * 32);
      float acc = bias;
#pragma unroll
      for (int k = 0; k < 8; ++k) acc = fmaf(zr[k], w[k], acc);
      *(unsigned short*)(A + s * 256 + ((o * 2) ^ ((s & 7) << 4))) =
          f2bf(fast_tanh(acc));
    }
  }
  __syncthreads();

  // E1: 128 -> 64 tanh (MFMA)
  mfma_layer<4, 1>(A, 256, B, 128, wpack + (size_t)416 * 512, eb1, lane, wv);
  __syncthreads();

  // E2 + softmax (VALU): e1[32][64] bf16 (B) -> gamma
#pragma unroll
  for (int p = 0; p < 2; ++p) {
    const int c = tid & 15;
    const int s = p * 16 + (tid >> 4);
    const int swz = (s & 7) << 4;
    float acc = eb2[c];
#pragma unroll
    for (int cb = 0; cb < 8; ++cb) {
      u16x8 ev = *(const u16x8*)(B + s * 128 + ((cb * 16) ^ swz));
#pragma unroll
      for (int i = 0; i < 8; ++i)
        acc = fmaf(bf2f(ev[i]), E2w[(cb * 8 + i) * 16 + c], acc);
    }
    float m = acc;
#pragma unroll
    for (int off = 8; off > 0; off >>= 1) m = fmaxf(m, __shfl_xor(m, off, 16));
    const float e = __expf(acc - m);
    float sum = e;
#pragma unroll
    for (int off = 8; off > 0; off >>= 1) sum += __shfl_xor(sum, off, 16);
    gamma[((size_t)blk * 32 + s) * 16 + c] = e / sum;
  }
}

// ---------------------------------------------------------------------------
// K2: GMM moment accumulation (unchanged; invisible in profile)
// ---------------------------------------------------------------------------
__global__ __launch_bounds__(256) void k2_stats(
    const float* __restrict__ zg, const float* __restrict__ gamma,
    float* __restrict__ stats)
{
  const int tid = threadIdx.x;
  const int k = tid & 15;
  const int chunk = blockIdx.x * 16 + (tid >> 4);
  const int s0 = chunk * 64;
  float m2[36], m1[8], gs = 0.f;
#pragma unroll
  for (int i = 0; i < 36; ++i) m2[i] = 0.f;
#pragma unroll
  for (int i = 0; i < 8; ++i) m1[i] = 0.f;

  for (int i = 0; i < 64; ++i) {
    const int n = s0 + i;
    const float4 za = *(const float4*)(zg + (size_t)n * 8);
    const float4 zb = *(const float4*)(zg + (size_t)n * 8 + 4);
    const float zv[8] = {za.x, za.y, za.z, za.w, zb.x, zb.y, zb.z, zb.w};
    const float g = gamma[(size_t)n * 16 + k];
    gs += g;
    float t[8];
#pragma unroll
    for (int l = 0; l < 8; ++l) { t[l] = g * zv[l]; m1[l] += t[l]; }
    int p = 0;
#pragma unroll
    for (int l = 0; l < 8; ++l)
#pragma unroll
      for (int m = l; m < 8; ++m) {
        m2[p] = fmaf(t[l], zv[m], m2[p]);
        ++p;
      }
  }
#pragma unroll
  for (int i = 0; i < 36; ++i) {
    m2[i] += __shfl_xor(m2[i], 16);
    m2[i] += __shfl_xor(m2[i], 32);
  }
#pragma unroll
  for (int i = 0; i < 8; ++i) {
    m1[i] += __shfl_xor(m1[i], 16);
    m1[i] += __shfl_xor(m1[i], 32);
  }
  gs += __shfl_xor(gs, 16);
  gs += __shfl_xor(gs, 32);

  if ((tid & 48) == 0) {
    float* sk = stats + k * 45;
#pragma unroll
    for (int i = 0; i < 36; ++i) atomicAdd(&sk[i], m2[i]);
#pragma unroll
    for (int i = 0; i < 8; ++i) atomicAdd(&sk[36 + i], m1[i]);
    atomicAdd(&sk[44], gs);
  }
}

// ---------------------------------------------------------------------------
// K3: finalize GMM params -> quadratic coefficients (unchanged)
// ---------------------------------------------------------------------------
__global__ void k3_finalize(const float* __restrict__ stats, float* __restrict__ coef)
{
  const int k = threadIdx.x;
  if (k >= 16) return;
  const float* sk = stats + k * 45;
  const float gs = sk[44];
  float mu[8];
#pragma unroll
  for (int l = 0; l < 8; ++l) mu[l] = sk[36 + l] / gs;

  float S[8][8];
  {
    int p = 0;
    for (int l = 0; l < 8; ++l)
      for (int m = l; m < 8; ++m) {
        const float v = sk[p++] / gs - mu[l] * mu[m];
        S[l][m] = v; S[m][l] = v;
      }
  }
  for (int l = 0; l < 8; ++l) S[l][l] += 1e-6f;

  float L[8][8];
  for (int i = 0; i < 8; ++i)
    for (int j = 0; j <= i; ++j) {
      float s = S[i][j];
      for (int t = 0; t < j; ++t) s -= L[i][t] * L[j][t];
      if (i == j) L[i][i] = sqrtf(s);
      else        L[i][j] = s / L[j][j];
    }
  float logdet = 0.f;
  for (int i = 0; i < 8; ++i) logdet += logf(L[i][i]);
  logdet *= 2.f;

  float U[8][8];
  for (int j = 0; j < 8; ++j) {
    U[j][j] = 1.f / L[j][j];
    for (int i = j + 1; i < 8; ++i) {
      float s = 0.f;
      for (int t = j; t < i; ++t) s += L[i][t] * U[t][j];
      U[i][j] = -s / L[i][i];
    }
  }
  float Amat[8][8];
  for (int l = 0; l < 8; ++l)
    for (int m = l; m < 8; ++m) {
      float s = 0.f;
      for (int i = m; i < 8; ++i) s += U[i][l] * U[i][m];
      Amat[l][m] = s; Amat[m][l] = s;
    }
  float c[8];
  for (int l = 0; l < 8; ++l) {
    float s = 0.f;
    for (int m = 0; m < 8; ++m) s += Amat[l][m] * mu[m];
    c[l] = s;
  }
  float muAmu = 0.f;
  for (int l = 0; l < 8; ++l) muAmu += c[l] * mu[l];

  const float LOG2PI = 1.8378770664093453f;
  const float cnst = logf(gs) - logf((float)NSAMP)
                   - 0.5f * (8.f * LOG2PI + logdet + muAmu);

  float* ck = coef + k * 48;
  {
    int p = 0;
    for (int l = 0; l < 8; ++l)
      for (int m = l; m < 8; ++m) {
        ck[p] = (l == m) ? (-0.5f * Amat[l][l]) : (-Amat[l][m]);
        ++p;
      }
  }
  for (int l = 0; l < 8; ++l) ck[36 + l] = c[l];
  ck[44] = cnst;
  ck[45] = 0.f; ck[46] = 0.f; ck[47] = 0.f;
}

// ---------------------------------------------------------------------------
// K4: per-sample energy + online LSE (unchanged)
// ---------------------------------------------------------------------------
__global__ __launch_bounds__(256) void k4_energy(
    const float* __restrict__ zg, const float* __restrict__ coef,
    float* __restrict__ prob)
{
  __shared__ float C[16 * 48];
  for (int i = threadIdx.x; i < 16 * 48; i += 256) C[i] = coef[i];
  __syncthreads();

  const int n = blockIdx.x * 256 + threadIdx.x;
  const float4 za = *(const float4*)(zg + (size_t)n * 8);
  const float4 zb = *(const float4*)(zg + (size_t)n * 8 + 4);
  const float z[8] = {za.x, za.y, za.z, za.w, zb.x, zb.y, zb.z, zb.w};

  float pr[36];
  {
    int p = 0;
#pragma unroll
    for (int l = 0; l < 8; ++l)
#pragma unroll
      for (int m = l; m < 8; ++m) pr[p++] = z[l] * z[m];
  }

  float mx = -1e30f, sm = 0.f;
#pragma unroll
  for (int k = 0; k < 16; ++k) {
    const float4* c4 = (const float4*)&C[k * 48];
    float acc = C[k * 48 + 44];
#pragma unroll
    for (int q = 0; q < 9; ++q) {
      const float4 t = c4[q];
      acc = fmaf(t.x, pr[q * 4 + 0], acc);
      acc = fmaf(t.y, pr[q * 4 + 1], acc);
      acc = fmaf(t.z, pr[q * 4 + 2], acc);
      acc = fmaf(t.w, pr[q * 4 + 3], acc);
    }
    {
      const float4 t = c4[9];
      acc = fmaf(t.x, z[0], acc); acc = fmaf(t.y, z[1], acc);
      acc = fmaf(t.z, z[2], acc); acc = fmaf(t.w, z[3], acc);
    }
    {
      const float4 t = c4[10];
      acc = fmaf(t.x, z[4], acc); acc = fmaf(t.y, z[5], acc);
      acc = fmaf(t.z, z[6], acc); acc = fmaf(t.w, z[7], acc);
    }
    const float nm = fmaxf(mx, acc);
    sm = sm * __expf(mx - nm) + __expf(acc - nm);
    mx = nm;
  }
  prob[n] = -(mx + __logf(sm));
}

// ---------------------------------------------------------------------------
extern "C" void kernel_launch(void* const* d_in, const int* in_sizes, int n_in,
                              void* d_out, int out_size, void* d_ws, size_t ws_size,
                              hipStream_t stream)
{
  const float* x   = (const float*)d_in[0];
  const float* W0  = (const float*)d_in[1];
  const float* b0  = (const float*)d_in[2];
  const float* W1  = (const float*)d_in[3];
  const float* b1  = (const float*)d_in[4];
  const float* W2  = (const float*)d_in[5];
  const float* b2  = (const float*)d_in[6];
  const float* W3  = (const float*)d_in[7];
  const float* b3  = (const float*)d_in[8];
  const float* E0w = (const float*)d_in[9];
  const float* eb0 = (const float*)d_in[10];
  const float* E1w = (const float*)d_in[11];
  const float* eb1 = (const float*)d_in[12];
  const float* E2w = (const float*)d_in[13];
  const float* eb2 = (const float*)d_in[14];

  float* out  = (float*)d_out;
  float* prob = out;              // [N]
  float* zg   = out + NSAMP;      // [N][8]

  // ws layout: wpack (432 frags * 512 bf16 = 442368 B, padded to 448 KB),
  // then gamma [N][16] fp32, stats, coef
  unsigned short* wpack = (unsigned short*)d_ws;
  float* ws    = (float*)d_ws;
  float* gamma = ws + 114688;                 // 448 KB / 4
  float* stats = gamma + (size_t)NSAMP * 16;  // 16*45
  float* coef  = stats + 768;                 // 16*48

  hipMemsetAsync(stats, 0, 16 * 45 * sizeof(float), stream);

  k0_pack<<<432, 64, 0, stream>>>(W0, W1, W2, E1w, wpack);
  k1_mfma<<<NSAMP / TMS, 256, 0, stream>>>(x, wpack, b0, b1, b2, W3, b3,
                                           E0w, eb0, eb1, E2w, eb2, zg, gamma);
  k2_stats<<<256, 256, 0, stream>>>(zg, gamma, stats);
  k3_finalize<<<1, 64, 0, stream>>>(stats, coef);
  k4_energy<<<NSAMP / 256, 256, 0, stream>>>(zg, coef, prob);
}

// Round 6
// 335.813 us; speedup vs baseline: 6.9723x; 2.2035x over previous
//
#include <hip/hip_runtime.h>
#include <math.h>

#define NSAMP 262144
#define TMS 32   // samples per block in k1

typedef __bf16  bf16x8 __attribute__((ext_vector_type(8)));
typedef float   f32x4  __attribute__((ext_vector_type(4)));
typedef unsigned short u16x8 __attribute__((ext_vector_type(8)));
typedef unsigned short u16x4 __attribute__((ext_vector_type(4)));

__device__ __forceinline__ float fast_tanh(float v) {
  float e = __expf(2.0f * v);
  return 1.0f - 2.0f / (e + 1.0f);
}
__device__ __forceinline__ unsigned short f2bf(float f) {
  unsigned u = __float_as_uint(f);
  unsigned r = (u + 0x7FFFu + ((u >> 16) & 1u)) >> 16;   // RNE
  return (unsigned short)r;
}
__device__ __forceinline__ float bf2f(unsigned short b) {
  return __uint_as_float(((unsigned)b) << 16);
}

// ---------------------------------------------------------------------------
// K0: pack W0,W1,W2,E1 (fp32 [K][N]) into bf16 MFMA B-fragments.
// frag f covers (nt,ks); lane l holds W[k = ks*32+(l>>4)*8+i][n = nt*16+(l&15)]
// frag ids: L1 [0,128) NKS=4 N=512 | L2 [128,384) NKS=16 N=256
//           L3 [384,416) NKS=8 N=64 | E1 [416,432) NKS=4 N=64
// ---------------------------------------------------------------------------
__global__ void k0_pack(const float* __restrict__ W0, const float* __restrict__ W1,
                        const float* __restrict__ W2, const float* __restrict__ E1w,
                        unsigned short* __restrict__ wpack)
{
  const int f = blockIdx.x;
  const int lane = threadIdx.x;
  const float* W; int NKS, N, local;
  if (f < 128)      { W = W0;  NKS = 4;  N = 512; local = f; }
  else if (f < 384) { W = W1;  NKS = 16; N = 256; local = f - 128; }
  else if (f < 416) { W = W2;  NKS = 8;  N = 64;  local = f - 384; }
  else              { W = E1w; NKS = 4;  N = 64;  local = f - 416; }
  const int nt = local / NKS, ks = local % NKS;
  const int n = nt * 16 + (lane & 15);
  const int kbase = ks * 32 + (lane >> 4) * 8;
  unsigned short* out = wpack + ((size_t)f * 64 + lane) * 8;
#pragma unroll
  for (int i = 0; i < 8; ++i)
    out[i] = f2bf(W[(size_t)(kbase + i) * N + n]);
}

// ---------------------------------------------------------------------------
// MFMA tanh layer: in/out are LDS bf16 [32][K or N] with byte-swizzle
// byte ^= ((row&7)<<4). Wave wv handles n-tiles [wv*NTPW, wv*NTPW+NTPW).
// ---------------------------------------------------------------------------
template<int NKS, int NTPW>
__device__ __forceinline__ void mfma_layer(
    const char* __restrict__ in, int inRowB, char* __restrict__ outb, int outRowB,
    const unsigned short* __restrict__ wp, const float* __restrict__ bias,
    int lane, int wv)
{
  const int l15 = lane & 15, lg = lane >> 4;
  const int sw = (l15 & 7) << 4;
  for (int t = 0; t < NTPW; ++t) {
    const int nt = wv * NTPW + t;
    const float bv = bias[nt * 16 + l15];
    f32x4 acc0 = {bv, bv, bv, bv}, acc1 = {bv, bv, bv, bv};
#pragma unroll
    for (int kc = 0; kc < NKS; kc += 4) {
      bf16x8 a0[4], a1[4], b[4];
#pragma unroll
      for (int q = 0; q < 4; ++q) {
        const int colb = (kc + q) * 64 + lg * 16;
        a0[q] = *(const bf16x8*)(in + l15 * inRowB + (colb ^ sw));
        a1[q] = *(const bf16x8*)(in + (16 + l15) * inRowB + (colb ^ sw));
        b[q]  = *(const bf16x8*)(wp + ((size_t)(nt * NKS + kc + q) * 64 + lane) * 8);
      }
#pragma unroll
      for (int q = 0; q < 4; ++q) {
        acc0 = __builtin_amdgcn_mfma_f32_16x16x32_bf16(a0[q], b[q], acc0, 0, 0, 0);
        acc1 = __builtin_amdgcn_mfma_f32_16x16x32_bf16(a1[q], b[q], acc1, 0, 0, 0);
      }
    }
#pragma unroll
    for (int r = 0; r < 4; ++r) {
      const int nb = (nt * 16 + l15) * 2;
      const int m0 = lg * 4 + r;
      *(unsigned short*)(outb + m0 * outRowB + (nb ^ ((m0 & 7) << 4))) =
          f2bf(fast_tanh(acc0[r]));
      const int m1 = m0 + 16;
      *(unsigned short*)(outb + m1 * outRowB + (nb ^ ((m1 & 7) << 4))) =
          f2bf(fast_tanh(acc1[r]));
    }
  }
}

// ---------------------------------------------------------------------------
// K1: fused MLP, MFMA for L1/L2/L3/E1, VALU for L4/E0/E2+softmax.
// ---------------------------------------------------------------------------
__global__ __launch_bounds__(256, 3) void k1_mfma(
    const float* __restrict__ x, const unsigned short* __restrict__ wpack,
    const float* __restrict__ b0, const float* __restrict__ b1,
    const float* __restrict__ b2,
    const float* __restrict__ W3, const float* __restrict__ b3,
    const float* __restrict__ E0w, const float* __restrict__ eb0,
    const float* __restrict__ eb1,
    const float* __restrict__ E2w, const float* __restrict__ eb2,
    float* __restrict__ zg, float* __restrict__ gamma)
{
  __shared__ char sm[49152];
  char* B = sm;            // 16 KB
  char* A = sm + 16384;    // 32 KB
  const int tid = threadIdx.x;
  const int lane = tid & 63, wv = tid >> 6;
  const int blk = blockIdx.x;

  // ---- stage x tile -> B: bf16 [32][128], rows 256B, swizzled ----
  {
    const float* xb = x + (size_t)blk * (TMS * 128);
#pragma unroll
    for (int p = 0; p < 4; ++p) {
      const int v = tid + p * 256;
      const float4 t = *(const float4*)(xb + v * 4);
      const int s = v >> 5, k0 = (v & 31) * 4;
      u16x4 h = { f2bf(t.x), f2bf(t.y), f2bf(t.z), f2bf(t.w) };
      *(u16x4*)(B + s * 256 + ((k0 * 2) ^ ((s & 7) << 4))) = h;
    }
  }
  __syncthreads();

  mfma_layer<4, 8>(B, 256, A, 1024, wpack, b0, lane, wv);
  __syncthreads();
  mfma_layer<16, 4>(A, 1024, B, 512, wpack + (size_t)128 * 512, b1, lane, wv);
  __syncthreads();
  mfma_layer<8, 1>(B, 512, A, 128, wpack + (size_t)384 * 512, b2, lane, wv);
  __syncthreads();

  // L4 (VALU): h3[32][64] bf16 (A) -> z fp32 [32][8] (B) + zg global
  {
    const int s = tid >> 3, d = tid & 7;
    const int swz = (s & 7) << 4;
    float acc = b3[d];
#pragma unroll
    for (int c = 0; c < 8; ++c) {
      u16x8 hv = *(const u16x8*)(A + s * 128 + ((c * 16) ^ swz));
#pragma unroll
      for (int i = 0; i < 8; ++i)
        acc = fmaf(bf2f(hv[i]), W3[(c * 8 + i) * 8 + d], acc);
    }
    *(float*)(B + (s * 8 + d) * 4) = acc;
    zg[(size_t)blk * 256 + tid] = acc;
  }
  __syncthreads();

  // E0 (VALU): z (B fp32) -> e0 bf16 [32][128] (A), rows 256B swizzled
  {
    const int o = tid & 127, half = tid >> 7;
    float w[8];
#pragma unroll
    for (int k = 0; k < 8; ++k) w[k] = E0w[k * 128 + o];
    const float bias = eb0[o];
#pragma unroll
    for (int j = 0; j < 16; ++j) {
      const int s = half * 16 + j;
      const float* zr = (const float*)(B + s * 32);
      float acc = bias;
#pragma unroll
      for (int k = 0; k < 8; ++k) acc = fmaf(zr[k], w[k], acc);
      *(unsigned short*)(A + s * 256 + ((o * 2) ^ ((s & 7) << 4))) =
          f2bf(fast_tanh(acc));
    }
  }
  __syncthreads();

  mfma_layer<4, 1>(A, 256, B, 128, wpack + (size_t)416 * 512, eb1, lane, wv);
  __syncthreads();

  // E2 + softmax (VALU): e1[32][64] bf16 (B) -> gamma
#pragma unroll
  for (int p = 0; p < 2; ++p) {
    const int c = tid & 15;
    const int s = p * 16 + (tid >> 4);
    const int swz = (s & 7) << 4;
    float acc = eb2[c];
#pragma unroll
    for (int cb = 0; cb < 8; ++cb) {
      u16x8 ev = *(const u16x8*)(B + s * 128 + ((cb * 16) ^ swz));
#pragma unroll
      for (int i = 0; i < 8; ++i)
        acc = fmaf(bf2f(ev[i]), E2w[(cb * 8 + i) * 16 + c], acc);
    }
    float m = acc;
#pragma unroll
    for (int off = 8; off > 0; off >>= 1) m = fmaxf(m, __shfl_xor(m, off, 16));
    const float e = __expf(acc - m);
    float sum = e;
#pragma unroll
    for (int off = 8; off > 0; off >>= 1) sum += __shfl_xor(sum, off, 16);
    gamma[((size_t)blk * 32 + s) * 16 + c] = e / sum;
  }
}

// ---------------------------------------------------------------------------
// K2a: moment partials. 1024 blocks x 256 samples each, LDS-staged.
// thread: k = tid&15, sub = tid>>4; sub s handles samples n = i*16+s.
// Output: part[blk][768], o = k*48 + p (p<36: zz, 36..43: z, 44: g, 45..47: 0)
// ---------------------------------------------------------------------------
__global__ __launch_bounds__(256) void k2a_partial(
    const float* __restrict__ zg, const float* __restrict__ gamma,
    float* __restrict__ part)
{
  __shared__ float zl[256 * 8];     // 8 KB
  __shared__ float gl[256 * 16];    // 16 KB
  __shared__ float red[4][16][46];  // 11.8 KB
  const int tid = threadIdx.x;
  const int blk = blockIdx.x;
  const int s0 = blk * 256;

  // stage z: thread -> sample s0+tid (32B, coalesced)
  {
    const float4 a = *(const float4*)(zg + (size_t)(s0 + tid) * 8);
    const float4 b = *(const float4*)(zg + (size_t)(s0 + tid) * 8 + 4);
    *(float4*)(&zl[tid * 8])     = a;
    *(float4*)(&zl[tid * 8 + 4]) = b;
  }
  // stage gamma: thread -> sample s0+tid's 16 gammas (64B, coalesced)
  {
    const float* gp = gamma + (size_t)(s0 + tid) * 16;
#pragma unroll
    for (int q = 0; q < 4; ++q)
      *(float4*)(&gl[tid * 16 + q * 4]) = *(const float4*)(gp + q * 4);
  }
  __syncthreads();

  const int k = tid & 15, sub = tid >> 4;
  float m2[36], m1[8], gs = 0.f;
#pragma unroll
  for (int i = 0; i < 36; ++i) m2[i] = 0.f;
#pragma unroll
  for (int i = 0; i < 8; ++i) m1[i] = 0.f;

#pragma unroll 4
  for (int i = 0; i < 16; ++i) {
    const int n = i * 16 + sub;
    const float4 za = *(const float4*)(&zl[n * 8]);
    const float4 zb = *(const float4*)(&zl[n * 8 + 4]);
    const float zv[8] = {za.x, za.y, za.z, za.w, zb.x, zb.y, zb.z, zb.w};
    const float g = gl[n * 16 + k];
    gs += g;
    float t[8];
#pragma unroll
    for (int l = 0; l < 8; ++l) { t[l] = g * zv[l]; m1[l] += t[l]; }
    int p = 0;
#pragma unroll
    for (int l = 0; l < 8; ++l)
#pragma unroll
      for (int m = l; m < 8; ++m) {
        m2[p] = fmaf(t[l], zv[m], m2[p]);
        ++p;
      }
  }

  // reduce 4 subs within wave
#pragma unroll
  for (int i = 0; i < 36; ++i) {
    m2[i] += __shfl_xor(m2[i], 16);
    m2[i] += __shfl_xor(m2[i], 32);
  }
#pragma unroll
  for (int i = 0; i < 8; ++i) {
    m1[i] += __shfl_xor(m1[i], 16);
    m1[i] += __shfl_xor(m1[i], 32);
  }
  gs += __shfl_xor(gs, 16);
  gs += __shfl_xor(gs, 32);

  const int lane = tid & 63, wv = tid >> 6;
  if (lane < 16) {
#pragma unroll
    for (int i = 0; i < 36; ++i) red[wv][lane][i] = m2[i];
#pragma unroll
    for (int i = 0; i < 8; ++i) red[wv][lane][36 + i] = m1[i];
    red[wv][lane][44] = gs;
  }
  __syncthreads();

  // cross-wave reduce + write partial (coalesced). 768 outputs, 256 threads:
  // STRIDE the loop (round-5 bug: `if (tid<768)` left k>=6 unwritten = poison).
  for (int o = tid; o < 768; o += 256) {
    const int kk = o / 48, p = o % 48;
    float v = 0.f;
    if (p < 45)
      v = red[0][kk][p] + red[1][kk][p] + red[2][kk][p] + red[3][kk][p];
    part[(size_t)blk * 768 + o] = v;
  }
}

// ---------------------------------------------------------------------------
// K2b: reduce part[1024][768] -> stats[768] (o = k*48+p). 24 blocks.
// ---------------------------------------------------------------------------
__global__ __launch_bounds__(256) void k2b_reduce(
    const float* __restrict__ part, float* __restrict__ stats)
{
  const int oi = blockIdx.x % 3, jc = blockIdx.x / 3;
  const int o = oi * 256 + threadIdx.x;
  float s = 0.f;
#pragma unroll 4
  for (int j = jc * 128; j < jc * 128 + 128; ++j)
    s += part[(size_t)j * 768 + o];
  atomicAdd(&stats[o], s);
}

// ---------------------------------------------------------------------------
// K3: finalize GMM params -> quadratic coefficients (stats stride 48)
// ---------------------------------------------------------------------------
__global__ void k3_finalize(const float* __restrict__ stats, float* __restrict__ coef)
{
  const int k = threadIdx.x;
  if (k >= 16) return;
  const float* sk = stats + k * 48;
  const float gs = sk[44];
  float mu[8];
#pragma unroll
  for (int l = 0; l < 8; ++l) mu[l] = sk[36 + l] / gs;

  float S[8][8];
  {
    int p = 0;
    for (int l = 0; l < 8; ++l)
      for (int m = l; m < 8; ++m) {
        const float v = sk[p++] / gs - mu[l] * mu[m];
        S[l][m] = v; S[m][l] = v;
      }
  }
  for (int l = 0; l < 8; ++l) S[l][l] += 1e-6f;

  float L[8][8];
  for (int i = 0; i < 8; ++i)
    for (int j = 0; j <= i; ++j) {
      float s = S[i][j];
      for (int t = 0; t < j; ++t) s -= L[i][t] * L[j][t];
      if (i == j) L[i][i] = sqrtf(s);
      else        L[i][j] = s / L[j][j];
    }
  float logdet = 0.f;
  for (int i = 0; i < 8; ++i) logdet += logf(L[i][i]);
  logdet *= 2.f;

  float U[8][8];
  for (int j = 0; j < 8; ++j) {
    U[j][j] = 1.f / L[j][j];
    for (int i = j + 1; i < 8; ++i) {
      float s = 0.f;
      for (int t = j; t < i; ++t) s += L[i][t] * U[t][j];
      U[i][j] = -s / L[i][i];
    }
  }
  float Amat[8][8];
  for (int l = 0; l < 8; ++l)
    for (int m = l; m < 8; ++m) {
      float s = 0.f;
      for (int i = m; i < 8; ++i) s += U[i][l] * U[i][m];
      Amat[l][m] = s; Amat[m][l] = s;
    }
  float c[8];
  for (int l = 0; l < 8; ++l) {
    float s = 0.f;
    for (int m = 0; m < 8; ++m) s += Amat[l][m] * mu[m];
    c[l] = s;
  }
  float muAmu = 0.f;
  for (int l = 0; l < 8; ++l) muAmu += c[l] * mu[l];

  const float LOG2PI = 1.8378770664093453f;
  const float cnst = logf(gs) - logf((float)NSAMP)
                   - 0.5f * (8.f * LOG2PI + logdet + muAmu);

  float* ck = coef + k * 48;
  {
    int p = 0;
    for (int l = 0; l < 8; ++l)
      for (int m = l; m < 8; ++m) {
        ck[p] = (l == m) ? (-0.5f * Amat[l][l]) : (-Amat[l][m]);
        ++p;
      }
  }
  for (int l = 0; l < 8; ++l) ck[36 + l] = c[l];
  ck[44] = cnst;
  ck[45] = 0.f; ck[46] = 0.f; ck[47] = 0.f;
}

// ---------------------------------------------------------------------------
// K4: per-sample energy + online LSE
// ---------------------------------------------------------------------------
__global__ __launch_bounds__(256) void k4_energy(
    const float* __restrict__ zg, const float* __restrict__ coef,
    float* __restrict__ prob)
{
  __shared__ float C[16 * 48];
  for (int i = threadIdx.x; i < 16 * 48; i += 256) C[i] = coef[i];
  __syncthreads();

  const int n = blockIdx.x * 256 + threadIdx.x;
  const float4 za = *(const float4*)(zg + (size_t)n * 8);
  const float4 zb = *(const float4*)(zg + (size_t)n * 8 + 4);
  const float z[8] = {za.x, za.y, za.z, za.w, zb.x, zb.y, zb.z, zb.w};

  float pr[36];
  {
    int p = 0;
#pragma unroll
    for (int l = 0; l < 8; ++l)
#pragma unroll
      for (int m = l; m < 8; ++m) pr[p++] = z[l] * z[m];
  }

  float mx = -1e30f, sm = 0.f;
#pragma unroll
  for (int k = 0; k < 16; ++k) {
    const float4* c4 = (const float4*)&C[k * 48];
    float acc = C[k * 48 + 44];
#pragma unroll
    for (int q = 0; q < 9; ++q) {
      const float4 t = c4[q];
      acc = fmaf(t.x, pr[q * 4 + 0], acc);
      acc = fmaf(t.y, pr[q * 4 + 1], acc);
      acc = fmaf(t.z, pr[q * 4 + 2], acc);
      acc = fmaf(t.w, pr[q * 4 + 3], acc);
    }
    {
      const float4 t = c4[9];
      acc = fmaf(t.x, z[0], acc); acc = fmaf(t.y, z[1], acc);
      acc = fmaf(t.z, z[2], acc); acc = fmaf(t.w, z[3], acc);
    }
    {
      const float4 t = c4[10];
      acc = fmaf(t.x, z[4], acc); acc = fmaf(t.y, z[5], acc);
      acc = fmaf(t.z, z[6], acc); acc = fmaf(t.w, z[7], acc);
    }
    const float nm = fmaxf(mx, acc);
    sm = sm * __expf(mx - nm) + __expf(acc - nm);
    mx = nm;
  }
  prob[n] = -(mx + __logf(sm));
}

// ---------------------------------------------------------------------------
extern "C" void kernel_launch(void* const* d_in, const int* in_sizes, int n_in,
                              void* d_out, int out_size, void* d_ws, size_t ws_size,
                              hipStream_t stream)
{
  const float* x   = (const float*)d_in[0];
  const float* W0  = (const float*)d_in[1];
  const float* b0  = (const float*)d_in[2];
  const float* W1  = (const float*)d_in[3];
  const float* b1  = (const float*)d_in[4];
  const float* W2  = (const float*)d_in[5];
  const float* b2  = (const float*)d_in[6];
  const float* W3  = (const float*)d_in[7];
  const float* b3  = (const float*)d_in[8];
  const float* E0w = (const float*)d_in[9];
  const float* eb0 = (const float*)d_in[10];
  const float* E1w = (const float*)d_in[11];
  const float* eb1 = (const float*)d_in[12];
  const float* E2w = (const float*)d_in[13];
  const float* eb2 = (const float*)d_in[14];

  float* out  = (float*)d_out;
  float* prob = out;              // [N]
  float* zg   = out + NSAMP;      // [N][8]

  // ws: wpack 448 KB | gamma [N][16] | stats 768 | coef 768 | part [1024][768]
  unsigned short* wpack = (unsigned short*)d_ws;
  float* ws    = (float*)d_ws;
  float* gamma = ws + 114688;
  float* stats = gamma + (size_t)NSAMP * 16;
  float* coef  = stats + 768;
  float* part  = coef + 768;

  hipMemsetAsync(stats, 0, 768 * sizeof(float), stream);

  k0_pack<<<432, 64, 0, stream>>>(W0, W1, W2, E1w, wpack);
  k1_mfma<<<NSAMP / TMS, 256, 0, stream>>>(x, wpack, b0, b1, b2, W3, b3,
                                           E0w, eb0, eb1, E2w, eb2, zg, gamma);
  k2a_partial<<<1024, 256, 0, stream>>>(zg, gamma, part);
  k2b_reduce<<<24, 256, 0, stream>>>(part, stats);
  k3_finalize<<<1, 64, 0, stream>>>(stats, coef);
  k4_energy<<<NSAMP / 256, 256, 0, stream>>>(zg, coef, prob);
}

// Round 7
// 271.308 us; speedup vs baseline: 8.6300x; 1.2378x over previous
//
#include <hip/hip_runtime.h>
#include <math.h>

#define NSAMP 262144
#define TMS 32   // samples per block in k1

typedef __bf16  bf16x8 __attribute__((ext_vector_type(8)));
typedef __bf16  bf16x4 __attribute__((ext_vector_type(4)));
typedef float   f32x4  __attribute__((ext_vector_type(4)));

__device__ __forceinline__ float fast_tanh(float v) {
  float e = __expf(2.0f * v);
  return 1.0f - 2.0f / (e + 1.0f);
}
__device__ __forceinline__ unsigned short f2bf(float f) {
  unsigned u = __float_as_uint(f);
  unsigned r = (u + 0x7FFFu + ((u >> 16) & 1u)) >> 16;   // RNE
  return (unsigned short)r;
}

// ---------------------------------------------------------------------------
// K0: pack all weights into bf16 MFMA *A-operand* fragments of W^T:
// lane l holds W[k = ks*32+(l>>4)*8+i][n = nt*16+(l&15)], zero-padded OOB.
// sections (frag id ranges):
//   L1 [0,128): NKS=4  N=512 | L2 [128,384): NKS=16 N=256
//   L3 [384,416): NKS=8 N=64 | E1 [416,432): NKS=4  N=64
//   E0 [432,440): NKS=1 N=128 K=8 | L4 [440,442): NKS=2 N=8->16 K=64
//   E2 [442,444): NKS=2 N=16 K=64
// ---------------------------------------------------------------------------
__global__ void k0_pack(const float* __restrict__ W0, const float* __restrict__ W1,
                        const float* __restrict__ W2, const float* __restrict__ E1w,
                        const float* __restrict__ E0w, const float* __restrict__ W3,
                        const float* __restrict__ E2w,
                        unsigned short* __restrict__ wpack)
{
  const int f = blockIdx.x;
  const int lane = threadIdx.x;
  const float* W; int NKS, N, Kreal, Nreal, local;
  if (f < 128)      { W = W0;  NKS = 4;  N = 512; Kreal = 128; Nreal = 512; local = f; }
  else if (f < 384) { W = W1;  NKS = 16; N = 256; Kreal = 512; Nreal = 256; local = f - 128; }
  else if (f < 416) { W = W2;  NKS = 8;  N = 64;  Kreal = 256; Nreal = 64;  local = f - 384; }
  else if (f < 432) { W = E1w; NKS = 4;  N = 64;  Kreal = 128; Nreal = 64;  local = f - 416; }
  else if (f < 440) { W = E0w; NKS = 1;  N = 128; Kreal = 8;   Nreal = 128; local = f - 432; }
  else if (f < 442) { W = W3;  NKS = 2;  N = 8;   Kreal = 64;  Nreal = 8;   local = f - 440; }
  else              { W = E2w; NKS = 2;  N = 16;  Kreal = 64;  Nreal = 16;  local = f - 442; }
  const int nt = local / NKS, ks = local % NKS;
  const int n = nt * 16 + (lane & 15);
  const int kbase = ks * 32 + (lane >> 4) * 8;
  unsigned short* out = wpack + ((size_t)f * 64 + lane) * 8;
#pragma unroll
  for (int i = 0; i < 8; ++i) {
    const int k = kbase + i;
    const float v = (k < Kreal && n < Nreal) ? W[(size_t)k * N + n] : 0.f;
    out[i] = f2bf(v);
  }
}

// ---------------------------------------------------------------------------
// Swapped-operand MFMA layers: D = W^T x act^T -> lane holds 4 consecutive
// out-feats of one sample => tanh + cvt_pk + single ds_write_b64 epilogue.
// Act frags cached in registers across n-tiles.
// ---------------------------------------------------------------------------
template<int NKS, int NTPW>   // variant A: acc transient per tile (NKS <= 4)
__device__ __forceinline__ void layerA(
    const char* __restrict__ in, int inRowB, char* __restrict__ outb, int outRowB,
    const unsigned short* __restrict__ wp, const float* __restrict__ bias,
    int lane, int wv)
{
  const int l15 = lane & 15, lg = lane >> 4;
  const int sw = (l15 & 7) << 4;
  bf16x8 a0[NKS], a1[NKS];
#pragma unroll
  for (int q = 0; q < NKS; ++q) {
    const int colb = q * 64 + lg * 16;
    a0[q] = *(const bf16x8*)(in + l15 * inRowB + (colb ^ sw));
    a1[q] = *(const bf16x8*)(in + (16 + l15) * inRowB + (colb ^ sw));
  }
#pragma unroll
  for (int t = 0; t < NTPW; ++t) {
    const int nt = wv * NTPW + t;
    const float4 bv = *(const float4*)(bias + nt * 16 + lg * 4);
    f32x4 acc0 = {bv.x, bv.y, bv.z, bv.w};
    f32x4 acc1 = acc0;
#pragma unroll
    for (int q = 0; q < NKS; ++q) {
      const bf16x8 b = *(const bf16x8*)(wp + ((size_t)(nt * NKS + q) * 64 + lane) * 8);
      acc0 = __builtin_amdgcn_mfma_f32_16x16x32_bf16(b, a0[q], acc0, 0, 0, 0);
      acc1 = __builtin_amdgcn_mfma_f32_16x16x32_bf16(b, a1[q], acc1, 0, 0, 0);
    }
    bf16x4 t0, t1;
#pragma unroll
    for (int r = 0; r < 4; ++r) {
      t0[r] = (__bf16)fast_tanh(acc0[r]);
      t1[r] = (__bf16)fast_tanh(acc1[r]);
    }
    const int fb = nt * 32 + lg * 8;
    *(bf16x4*)(outb + l15 * outRowB + (fb ^ sw)) = t0;
    *(bf16x4*)(outb + (16 + l15) * outRowB + (fb ^ sw)) = t1;
  }
}

template<int NKS, int NTPW>   // variant B: persistent acc, kc chunks of 4
__device__ __forceinline__ void layerB(
    const char* __restrict__ in, int inRowB, char* __restrict__ outb, int outRowB,
    const unsigned short* __restrict__ wp, const float* __restrict__ bias,
    int lane, int wv)
{
  const int l15 = lane & 15, lg = lane >> 4;
  const int sw = (l15 & 7) << 4;
  f32x4 acc0[NTPW], acc1[NTPW];
#pragma unroll
  for (int t = 0; t < NTPW; ++t) {
    const float4 bv = *(const float4*)(bias + (wv * NTPW + t) * 16 + lg * 4);
    acc0[t] = {bv.x, bv.y, bv.z, bv.w};
    acc1[t] = acc0[t];
  }
#pragma unroll
  for (int ch = 0; ch < NKS / 4; ++ch) {
    bf16x8 a0[4], a1[4];
#pragma unroll
    for (int q = 0; q < 4; ++q) {
      const int colb = (ch * 4 + q) * 64 + lg * 16;
      a0[q] = *(const bf16x8*)(in + l15 * inRowB + (colb ^ sw));
      a1[q] = *(const bf16x8*)(in + (16 + l15) * inRowB + (colb ^ sw));
    }
#pragma unroll
    for (int t = 0; t < NTPW; ++t) {
      const int nt = wv * NTPW + t;
#pragma unroll
      for (int q = 0; q < 4; ++q) {
        const bf16x8 b = *(const bf16x8*)(wp + ((size_t)(nt * NKS + ch * 4 + q) * 64 + lane) * 8);
        acc0[t] = __builtin_amdgcn_mfma_f32_16x16x32_bf16(b, a0[q], acc0[t], 0, 0, 0);
        acc1[t] = __builtin_amdgcn_mfma_f32_16x16x32_bf16(b, a1[q], acc1[t], 0, 0, 0);
      }
    }
  }
#pragma unroll
  for (int t = 0; t < NTPW; ++t) {
    const int nt = wv * NTPW + t;
    bf16x4 t0, t1;
#pragma unroll
    for (int r = 0; r < 4; ++r) {
      t0[r] = (__bf16)fast_tanh(acc0[t][r]);
      t1[r] = (__bf16)fast_tanh(acc1[t][r]);
    }
    const int fb = nt * 32 + lg * 8;
    *(bf16x4*)(outb + l15 * outRowB + (fb ^ sw)) = t0;
    *(bf16x4*)(outb + (16 + l15) * outRowB + (fb ^ sw)) = t1;
  }
}

// ---------------------------------------------------------------------------
// K1: fully-MFMA fused MLP (swapped operands everywhere).
// LDS: B [0,16K) : x(8K) -> L2out(16K) -> e1(4K)
//      A [16K,48K): L1out(32K) -> L3out(4K) -> E0out(8K); zf fp32 at A+8K(1K)
// ---------------------------------------------------------------------------
__global__ __launch_bounds__(256, 3) void k1_mfma(
    const float* __restrict__ x, const unsigned short* __restrict__ wpack,
    const float* __restrict__ b0, const float* __restrict__ b1,
    const float* __restrict__ b2, const float* __restrict__ b3,
    const float* __restrict__ eb0, const float* __restrict__ eb1,
    const float* __restrict__ eb2,
    float* __restrict__ zg, float* __restrict__ gamma)
{
  __shared__ char sm[49152];
  char* B = sm;            // 16 KB
  char* A = sm + 16384;    // 32 KB
  float* zfl = (float*)(A + 8192);   // fp32 z [32][8]
  const int tid = threadIdx.x;
  const int lane = tid & 63, wv = tid >> 6;
  const int l15 = lane & 15, lg = lane >> 4;
  const int sw = (l15 & 7) << 4;
  const int blk = blockIdx.x;

  // ---- stage x -> B: bf16 [32][128], rowB 256, swizzled ----
  {
    const float* xb = x + (size_t)blk * (TMS * 128);
#pragma unroll
    for (int p = 0; p < 4; ++p) {
      const int v = tid + p * 256;
      const float4 t = *(const float4*)(xb + v * 4);
      const int s = v >> 5, k0 = (v & 31) * 4;
      bf16x4 h = {(__bf16)t.x, (__bf16)t.y, (__bf16)t.z, (__bf16)t.w};
      *(bf16x4*)(B + s * 256 + ((k0 * 2) ^ ((s & 7) << 4))) = h;
    }
  }
  __syncthreads();

  layerA<4, 8>(B, 256, A, 1024, wpack, b0, lane, wv);                       // L1
  __syncthreads();
  layerB<16, 4>(A, 1024, B, 512, wpack + (size_t)128 * 512, b1, lane, wv);  // L2
  __syncthreads();
  layerB<8, 1>(B, 512, A, 128, wpack + (size_t)384 * 512, b2, lane, wv);    // L3
  __syncthreads();

  // ---- L4 (MFMA, wave 0): h3 -> z (fp32), N padded 8->16 ----
  if (wv == 0) {
    bf16x8 a0[2], a1[2];
#pragma unroll
    for (int q = 0; q < 2; ++q) {
      const int colb = q * 64 + lg * 16;
      a0[q] = *(const bf16x8*)(A + l15 * 128 + (colb ^ sw));
      a1[q] = *(const bf16x8*)(A + (16 + l15) * 128 + (colb ^ sw));
    }
    float4 bv;
    if (lg < 2) bv = *(const float4*)(b3 + lg * 4);
    else { bv.x = bv.y = bv.z = bv.w = 0.f; }
    f32x4 acc0 = {bv.x, bv.y, bv.z, bv.w};
    f32x4 acc1 = acc0;
    const unsigned short* wp = wpack + (size_t)440 * 512;
#pragma unroll
    for (int q = 0; q < 2; ++q) {
      const bf16x8 b = *(const bf16x8*)(wp + ((size_t)q * 64 + lane) * 8);
      acc0 = __builtin_amdgcn_mfma_f32_16x16x32_bf16(b, a0[q], acc0, 0, 0, 0);
      acc1 = __builtin_amdgcn_mfma_f32_16x16x32_bf16(b, a1[q], acc1, 0, 0, 0);
    }
    if (lg < 2) {
      *(f32x4*)(zfl + l15 * 8 + lg * 4) = acc0;
      *(f32x4*)(zfl + (16 + l15) * 8 + lg * 4) = acc1;
      *(f32x4*)(zg + ((size_t)blk * 32 + l15) * 8 + lg * 4) = acc0;
      *(f32x4*)(zg + ((size_t)blk * 32 + 16 + l15) * 8 + lg * 4) = acc1;
    }
  }
  __syncthreads();

  // ---- E0 (MFMA, all waves): z -> e0 [32][128]. K=8 padded to 32 via
  // zero wpack frags; act frags broadcast-read (finite), k>=8 lanes killed
  // by the zero weights. ----
  {
    const float* zr0 = zfl + l15 * 8;
    const float* zr1 = zfl + (16 + l15) * 8;
    const float4 p0 = *(const float4*)zr0, p1 = *(const float4*)(zr0 + 4);
    const float4 q0 = *(const float4*)zr1, q1 = *(const float4*)(zr1 + 4);
    bf16x8 az0 = {(__bf16)p0.x, (__bf16)p0.y, (__bf16)p0.z, (__bf16)p0.w,
                  (__bf16)p1.x, (__bf16)p1.y, (__bf16)p1.z, (__bf16)p1.w};
    bf16x8 az1 = {(__bf16)q0.x, (__bf16)q0.y, (__bf16)q0.z, (__bf16)q0.w,
                  (__bf16)q1.x, (__bf16)q1.y, (__bf16)q1.z, (__bf16)q1.w};
    const unsigned short* wp = wpack + (size_t)432 * 512;
#pragma unroll
    for (int t = 0; t < 2; ++t) {
      const int nt = wv * 2 + t;
      const float4 bv = *(const float4*)(eb0 + nt * 16 + lg * 4);
      f32x4 acc0 = {bv.x, bv.y, bv.z, bv.w};
      f32x4 acc1 = acc0;
      const bf16x8 b = *(const bf16x8*)(wp + ((size_t)nt * 64 + lane) * 8);
      acc0 = __builtin_amdgcn_mfma_f32_16x16x32_bf16(b, az0, acc0, 0, 0, 0);
      acc1 = __builtin_amdgcn_mfma_f32_16x16x32_bf16(b, az1, acc1, 0, 0, 0);
      bf16x4 t0, t1;
#pragma unroll
      for (int r = 0; r < 4; ++r) {
        t0[r] = (__bf16)fast_tanh(acc0[r]);
        t1[r] = (__bf16)fast_tanh(acc1[r]);
      }
      const int fb = nt * 32 + lg * 8;
      *(bf16x4*)(A + l15 * 256 + (fb ^ sw)) = t0;
      *(bf16x4*)(A + (16 + l15) * 256 + (fb ^ sw)) = t1;
    }
  }
  __syncthreads();

  layerA<4, 1>(A, 256, B, 128, wpack + (size_t)416 * 512, eb1, lane, wv);   // E1
  __syncthreads();

  // ---- E2 + softmax (MFMA, wave 0): e1 -> gamma. comps along lg dim. ----
  if (wv == 0) {
    bf16x8 a0[2], a1[2];
#pragma unroll
    for (int q = 0; q < 2; ++q) {
      const int colb = q * 64 + lg * 16;
      a0[q] = *(const bf16x8*)(B + l15 * 128 + (colb ^ sw));
      a1[q] = *(const bf16x8*)(B + (16 + l15) * 128 + (colb ^ sw));
    }
    const float4 bv = *(const float4*)(eb2 + lg * 4);
    f32x4 acc0 = {bv.x, bv.y, bv.z, bv.w};
    f32x4 acc1 = acc0;
    const unsigned short* wp = wpack + (size_t)442 * 512;
#pragma unroll
    for (int q = 0; q < 2; ++q) {
      const bf16x8 b = *(const bf16x8*)(wp + ((size_t)q * 64 + lane) * 8);
      acc0 = __builtin_amdgcn_mfma_f32_16x16x32_bf16(b, a0[q], acc0, 0, 0, 0);
      acc1 = __builtin_amdgcn_mfma_f32_16x16x32_bf16(b, a1[q], acc1, 0, 0, 0);
    }
    auto softmax_store = [&](f32x4 acc, int sb) {
      float m = fmaxf(fmaxf(acc[0], acc[1]), fmaxf(acc[2], acc[3]));
      m = fmaxf(m, __shfl_xor(m, 16));
      m = fmaxf(m, __shfl_xor(m, 32));
      float e0 = __expf(acc[0] - m), e1 = __expf(acc[1] - m);
      float e2 = __expf(acc[2] - m), e3 = __expf(acc[3] - m);
      float s = e0 + e1 + e2 + e3;
      s += __shfl_xor(s, 16);
      s += __shfl_xor(s, 32);
      const float inv = 1.0f / s;
      float4 g = {e0 * inv, e1 * inv, e2 * inv, e3 * inv};
      *(float4*)(gamma + ((size_t)blk * 32 + sb + l15) * 16 + lg * 4) = g;
    };
    softmax_store(acc0, 0);
    softmax_store(acc1, 16);
  }
}

// ---------------------------------------------------------------------------
// K2a: moment partials. 1024 blocks x 256 samples each, LDS-staged.
// ---------------------------------------------------------------------------
__global__ __launch_bounds__(256) void k2a_partial(
    const float* __restrict__ zg, const float* __restrict__ gamma,
    float* __restrict__ part)
{
  __shared__ float zl[256 * 8];
  __shared__ float gl[256 * 16];
  __shared__ float red[4][16][46];
  const int tid = threadIdx.x;
  const int blk = blockIdx.x;
  const int s0 = blk * 256;

  {
    const float4 a = *(const float4*)(zg + (size_t)(s0 + tid) * 8);
    const float4 b = *(const float4*)(zg + (size_t)(s0 + tid) * 8 + 4);
    *(float4*)(&zl[tid * 8])     = a;
    *(float4*)(&zl[tid * 8 + 4]) = b;
  }
  {
    const float* gp = gamma + (size_t)(s0 + tid) * 16;
#pragma unroll
    for (int q = 0; q < 4; ++q)
      *(float4*)(&gl[tid * 16 + q * 4]) = *(const float4*)(gp + q * 4);
  }
  __syncthreads();

  const int k = tid & 15, sub = tid >> 4;
  float m2[36], m1[8], gs = 0.f;
#pragma unroll
  for (int i = 0; i < 36; ++i) m2[i] = 0.f;
#pragma unroll
  for (int i = 0; i < 8; ++i) m1[i] = 0.f;

#pragma unroll 4
  for (int i = 0; i < 16; ++i) {
    const int n = i * 16 + sub;
    const float4 za = *(const float4*)(&zl[n * 8]);
    const float4 zb = *(const float4*)(&zl[n * 8 + 4]);
    const float zv[8] = {za.x, za.y, za.z, za.w, zb.x, zb.y, zb.z, zb.w};
    const float g = gl[n * 16 + k];
    gs += g;
    float t[8];
#pragma unroll
    for (int l = 0; l < 8; ++l) { t[l] = g * zv[l]; m1[l] += t[l]; }
    int p = 0;
#pragma unroll
    for (int l = 0; l < 8; ++l)
#pragma unroll
      for (int m = l; m < 8; ++m) {
        m2[p] = fmaf(t[l], zv[m], m2[p]);
        ++p;
      }
  }

#pragma unroll
  for (int i = 0; i < 36; ++i) {
    m2[i] += __shfl_xor(m2[i], 16);
    m2[i] += __shfl_xor(m2[i], 32);
  }
#pragma unroll
  for (int i = 0; i < 8; ++i) {
    m1[i] += __shfl_xor(m1[i], 16);
    m1[i] += __shfl_xor(m1[i], 32);
  }
  gs += __shfl_xor(gs, 16);
  gs += __shfl_xor(gs, 32);

  const int lane = tid & 63, wv = tid >> 6;
  if (lane < 16) {
#pragma unroll
    for (int i = 0; i < 36; ++i) red[wv][lane][i] = m2[i];
#pragma unroll
    for (int i = 0; i < 8; ++i) red[wv][lane][36 + i] = m1[i];
    red[wv][lane][44] = gs;
  }
  __syncthreads();

  for (int o = tid; o < 768; o += 256) {
    const int kk = o / 48, p = o % 48;
    float v = 0.f;
    if (p < 45)
      v = red[0][kk][p] + red[1][kk][p] + red[2][kk][p] + red[3][kk][p];
    part[(size_t)blk * 768 + o] = v;
  }
}

// ---------------------------------------------------------------------------
// K2b: reduce part[1024][768] -> stats[768]. 24 blocks.
// ---------------------------------------------------------------------------
__global__ __launch_bounds__(256) void k2b_reduce(
    const float* __restrict__ part, float* __restrict__ stats)
{
  const int oi = blockIdx.x % 3, jc = blockIdx.x / 3;
  const int o = oi * 256 + threadIdx.x;
  float s = 0.f;
#pragma unroll 4
  for (int j = jc * 128; j < jc * 128 + 128; ++j)
    s += part[(size_t)j * 768 + o];
  atomicAdd(&stats[o], s);
}

// ---------------------------------------------------------------------------
// K3: finalize GMM params -> quadratic coefficients (stats stride 48)
// ---------------------------------------------------------------------------
__global__ void k3_finalize(const float* __restrict__ stats, float* __restrict__ coef)
{
  const int k = threadIdx.x;
  if (k >= 16) return;
  const float* sk = stats + k * 48;
  const float gs = sk[44];
  float mu[8];
#pragma unroll
  for (int l = 0; l < 8; ++l) mu[l] = sk[36 + l] / gs;

  float S[8][8];
  {
    int p = 0;
    for (int l = 0; l < 8; ++l)
      for (int m = l; m < 8; ++m) {
        const float v = sk[p++] / gs - mu[l] * mu[m];
        S[l][m] = v; S[m][l] = v;
      }
  }
  for (int l = 0; l < 8; ++l) S[l][l] += 1e-6f;

  float L[8][8];
  for (int i = 0; i < 8; ++i)
    for (int j = 0; j <= i; ++j) {
      float s = S[i][j];
      for (int t = 0; t < j; ++t) s -= L[i][t] * L[j][t];
      if (i == j) L[i][i] = sqrtf(s);
      else        L[i][j] = s / L[j][j];
    }
  float logdet = 0.f;
  for (int i = 0; i < 8; ++i) logdet += logf(L[i][i]);
  logdet *= 2.f;

  float U[8][8];
  for (int j = 0; j < 8; ++j) {
    U[j][j] = 1.f / L[j][j];
    for (int i = j + 1; i < 8; ++i) {
      float s = 0.f;
      for (int t = j; t < i; ++t) s += L[i][t] * U[t][j];
      U[i][j] = -s / L[i][i];
    }
  }
  float Amat[8][8];
  for (int l = 0; l < 8; ++l)
    for (int m = l; m < 8; ++m) {
      float s = 0.f;
      for (int i = m; i < 8; ++i) s += U[i][l] * U[i][m];
      Amat[l][m] = s; Amat[m][l] = s;
    }
  float c[8];
  for (int l = 0; l < 8; ++l) {
    float s = 0.f;
    for (int m = 0; m < 8; ++m) s += Amat[l][m] * mu[m];
    c[l] = s;
  }
  float muAmu = 0.f;
  for (int l = 0; l < 8; ++l) muAmu += c[l] * mu[l];

  const float LOG2PI = 1.8378770664093453f;
  const float cnst = logf(gs) - logf((float)NSAMP)
                   - 0.5f * (8.f * LOG2PI + logdet + muAmu);

  float* ck = coef + k * 48;
  {
    int p = 0;
    for (int l = 0; l < 8; ++l)
      for (int m = l; m < 8; ++m) {
        ck[p] = (l == m) ? (-0.5f * Amat[l][l]) : (-Amat[l][m]);
        ++p;
      }
  }
  for (int l = 0; l < 8; ++l) ck[36 + l] = c[l];
  ck[44] = cnst;
  ck[45] = 0.f; ck[46] = 0.f; ck[47] = 0.f;
}

// ---------------------------------------------------------------------------
// K4: per-sample energy + online LSE
// ---------------------------------------------------------------------------
__global__ __launch_bounds__(256) void k4_energy(
    const float* __restrict__ zg, const float* __restrict__ coef,
    float* __restrict__ prob)
{
  __shared__ float C[16 * 48];
  for (int i = threadIdx.x; i < 16 * 48; i += 256) C[i] = coef[i];
  __syncthreads();

  const int n = blockIdx.x * 256 + threadIdx.x;
  const float4 za = *(const float4*)(zg + (size_t)n * 8);
  const float4 zb = *(const float4*)(zg + (size_t)n * 8 + 4);
  const float z[8] = {za.x, za.y, za.z, za.w, zb.x, zb.y, zb.z, zb.w};

  float pr[36];
  {
    int p = 0;
#pragma unroll
    for (int l = 0; l < 8; ++l)
#pragma unroll
      for (int m = l; m < 8; ++m) pr[p++] = z[l] * z[m];
  }

  float mx = -1e30f, sm = 0.f;
#pragma unroll
  for (int k = 0; k < 16; ++k) {
    const float4* c4 = (const float4*)&C[k * 48];
    float acc = C[k * 48 + 44];
#pragma unroll
    for (int q = 0; q < 9; ++q) {
      const float4 t = c4[q];
      acc = fmaf(t.x, pr[q * 4 + 0], acc);
      acc = fmaf(t.y, pr[q * 4 + 1], acc);
      acc = fmaf(t.z, pr[q * 4 + 2], acc);
      acc = fmaf(t.w, pr[q * 4 + 3], acc);
    }
    {
      const float4 t = c4[9];
      acc = fmaf(t.x, z[0], acc); acc = fmaf(t.y, z[1], acc);
      acc = fmaf(t.z, z[2], acc); acc = fmaf(t.w, z[3], acc);
    }
    {
      const float4 t = c4[10];
      acc = fmaf(t.x, z[4], acc); acc = fmaf(t.y, z[5], acc);
      acc = fmaf(t.z, z[6], acc); acc = fmaf(t.w, z[7], acc);
    }
    const float nm = fmaxf(mx, acc);
    sm = sm * __expf(mx - nm) + __expf(acc - nm);
    mx = nm;
  }
  prob[n] = -(mx + __logf(sm));
}

// ---------------------------------------------------------------------------
extern "C" void kernel_launch(void* const* d_in, const int* in_sizes, int n_in,
                              void* d_out, int out_size, void* d_ws, size_t ws_size,
                              hipStream_t stream)
{
  const float* x   = (const float*)d_in[0];
  const float* W0  = (const float*)d_in[1];
  const float* b0  = (const float*)d_in[2];
  const float* W1  = (const float*)d_in[3];
  const float* b1  = (const float*)d_in[4];
  const float* W2  = (const float*)d_in[5];
  const float* b2  = (const float*)d_in[6];
  const float* W3  = (const float*)d_in[7];
  const float* b3  = (const float*)d_in[8];
  const float* E0w = (const float*)d_in[9];
  const float* eb0 = (const float*)d_in[10];
  const float* E1w = (const float*)d_in[11];
  const float* eb1 = (const float*)d_in[12];
  const float* E2w = (const float*)d_in[13];
  const float* eb2 = (const float*)d_in[14];

  float* out  = (float*)d_out;
  float* prob = out;              // [N]
  float* zg   = out + NSAMP;      // [N][8]

  // ws: wpack (444 frags * 512 B, region padded to 448 KB) | gamma [N][16]
  //   | stats 768 | coef 768 | part [1024][768]
  unsigned short* wpack = (unsigned short*)d_ws;
  float* ws    = (float*)d_ws;
  float* gamma = ws + 114688;
  float* stats = gamma + (size_t)NSAMP * 16;
  float* coef  = stats + 768;
  float* part  = coef + 768;

  hipMemsetAsync(stats, 0, 768 * sizeof(float), stream);

  k0_pack<<<444, 64, 0, stream>>>(W0, W1, W2, E1w, E0w, W3, E2w, wpack);
  k1_mfma<<<NSAMP / TMS, 256, 0, stream>>>(x, wpack, b0, b1, b2, b3,
                                           eb0, eb1, eb2, zg, gamma);
  k2a_partial<<<1024, 256, 0, stream>>>(zg, gamma, part);
  k2b_reduce<<<24, 256, 0, stream>>>(part, stats);
  k3_finalize<<<1, 64, 0, stream>>>(stats, coef);
  k4_energy<<<NSAMP / 256, 256, 0, stream>>>(zg, coef, prob);
}

// Round 8
// 263.634 us; speedup vs baseline: 8.8812x; 1.0291x over previous
//
#include <hip/hip_runtime.h>
#include <math.h>

#define NSAMP 262144
#define TMS 64   // samples per block in k1

typedef __bf16  bf16x8 __attribute__((ext_vector_type(8)));
typedef __bf16  bf16x4 __attribute__((ext_vector_type(4)));
typedef float   f32x4  __attribute__((ext_vector_type(4)));

__device__ __forceinline__ float fast_tanh(float v) {
  float e = __expf(2.0f * v);
  return 1.0f - 2.0f / (e + 1.0f);
}
__device__ __forceinline__ unsigned short f2bf(float f) {
  unsigned u = __float_as_uint(f);
  unsigned r = (u + 0x7FFFu + ((u >> 16) & 1u)) >> 16;   // RNE
  return (unsigned short)r;
}

// ---------------------------------------------------------------------------
// K0: pack all weights into bf16 MFMA *A-operand* fragments of W^T:
// lane l holds W[k = ks*32+(l>>4)*8+i][n = nt*16+(l&15)], zero-padded OOB.
// sections: L1 [0,128) NKS=4 N=512 | L2 [128,384) NKS=16 N=256
//   L3 [384,416) NKS=8 N=64 | E1 [416,432) NKS=4 N=64
//   E0 [432,440) NKS=1 N=128 K=8 | L4 [440,442) NKS=2 N=8->16 K=64
//   E2 [442,444) NKS=2 N=16 K=64
// ---------------------------------------------------------------------------
__global__ void k0_pack(const float* __restrict__ W0, const float* __restrict__ W1,
                        const float* __restrict__ W2, const float* __restrict__ E1w,
                        const float* __restrict__ E0w, const float* __restrict__ W3,
                        const float* __restrict__ E2w,
                        unsigned short* __restrict__ wpack)
{
  const int f = blockIdx.x;
  const int lane = threadIdx.x;
  const float* W; int NKS, N, Kreal, Nreal, local;
  if (f < 128)      { W = W0;  NKS = 4;  N = 512; Kreal = 128; Nreal = 512; local = f; }
  else if (f < 384) { W = W1;  NKS = 16; N = 256; Kreal = 512; Nreal = 256; local = f - 128; }
  else if (f < 416) { W = W2;  NKS = 8;  N = 64;  Kreal = 256; Nreal = 64;  local = f - 384; }
  else if (f < 432) { W = E1w; NKS = 4;  N = 64;  Kreal = 128; Nreal = 64;  local = f - 416; }
  else if (f < 440) { W = E0w; NKS = 1;  N = 128; Kreal = 8;   Nreal = 128; local = f - 432; }
  else if (f < 442) { W = W3;  NKS = 2;  N = 8;   Kreal = 64;  Nreal = 8;   local = f - 440; }
  else              { W = E2w; NKS = 2;  N = 16;  Kreal = 64;  Nreal = 16;  local = f - 442; }
  const int nt = local / NKS, ks = local % NKS;
  const int n = nt * 16 + (lane & 15);
  const int kbase = ks * 32 + (lane >> 4) * 8;
  unsigned short* out = wpack + ((size_t)f * 64 + lane) * 8;
#pragma unroll
  for (int i = 0; i < 8; ++i) {
    const int k = kbase + i;
    const float v = (k < Kreal && n < Nreal) ? W[(size_t)k * N + n] : 0.f;
    out[i] = f2bf(v);
  }
}

// ---------------------------------------------------------------------------
// Swapped-operand layer, NKS=4 (a-frags cached across tiles), 4 sample groups.
// frag = fragBase + nt*4 + q; store col relative to this section's n=0.
// ---------------------------------------------------------------------------
template<int NTPW>
__device__ __forceinline__ void layer_nks4(
    const char* __restrict__ in, int inRowB, char* __restrict__ outb, int outRowB,
    const unsigned short* __restrict__ wp, int fragBase,
    const float* __restrict__ bias, int lane, int wv)
{
  const int l15 = lane & 15, lg = lane >> 4;
  const int sw = (l15 & 7) << 4;
  bf16x8 a[4][4];
#pragma unroll
  for (int sg = 0; sg < 4; ++sg)
#pragma unroll
    for (int q = 0; q < 4; ++q)
      a[sg][q] = *(const bf16x8*)(in + (sg * 16 + l15) * inRowB + ((q * 64 + lg * 16) ^ sw));
#pragma unroll
  for (int t = 0; t < NTPW; ++t) {
    const int nt = wv * NTPW + t;
    const float4 bv = *(const float4*)(bias + nt * 16 + lg * 4);
    f32x4 acc[4];
#pragma unroll
    for (int sg = 0; sg < 4; ++sg) acc[sg] = {bv.x, bv.y, bv.z, bv.w};
#pragma unroll
    for (int q = 0; q < 4; ++q) {
      const bf16x8 w = *(const bf16x8*)(wp + ((size_t)(fragBase + nt * 4 + q) * 64 + lane) * 8);
#pragma unroll
      for (int sg = 0; sg < 4; ++sg)
        acc[sg] = __builtin_amdgcn_mfma_f32_16x16x32_bf16(w, a[sg][q], acc[sg], 0, 0, 0);
    }
#pragma unroll
    for (int sg = 0; sg < 4; ++sg) {
      bf16x4 tv;
#pragma unroll
      for (int r = 0; r < 4; ++r) tv[r] = (__bf16)fast_tanh(acc[sg][r]);
      *(bf16x4*)(outb + (sg * 16 + l15) * outRowB + ((nt * 32 + lg * 8) ^ sw)) = tv;
    }
  }
}

// ---------------------------------------------------------------------------
// L2 partial accumulation: K-half of 256 (2 chunks x 4 kfrags) into persistent
// acc[4 tiles][4 sg]. H1 rows 512B hold the current L1 half (relative k).
// ---------------------------------------------------------------------------
template<int NCH>
__device__ __forceinline__ void l2_accum(
    const char* __restrict__ H1, const unsigned short* __restrict__ wp,
    int ksOff, f32x4 (&acc)[4][4], int lane, int wv)
{
  const int l15 = lane & 15, lg = lane >> 4;
  const int sw = (l15 & 7) << 4;
#pragma unroll
  for (int ch = 0; ch < NCH; ++ch) {
    bf16x8 a[4][4];
#pragma unroll
    for (int sg = 0; sg < 4; ++sg)
#pragma unroll
      for (int q = 0; q < 4; ++q)
        a[sg][q] = *(const bf16x8*)(H1 + (sg * 16 + l15) * 512 + (((ch * 4 + q) * 64 + lg * 16) ^ sw));
#pragma unroll
    for (int t = 0; t < 4; ++t) {
      const int nt = wv * 4 + t;
#pragma unroll
      for (int q = 0; q < 4; ++q) {
        const bf16x8 w = *(const bf16x8*)(wp + ((size_t)(128 + nt * 16 + ksOff + ch * 4 + q) * 64 + lane) * 8);
#pragma unroll
        for (int sg = 0; sg < 4; ++sg)
          acc[t][sg] = __builtin_amdgcn_mfma_f32_16x16x32_bf16(w, a[sg][q], acc[t][sg], 0, 0, 0);
      }
    }
  }
}

// ---------------------------------------------------------------------------
// K1: fused MLP, TMS=64, half-pass L1/L2. LDS 80 KB -> 2 blocks/CU.
//  H1 [0,32K): L1out half -> (reuse) E0out
//  H2 [32K,64K): L2out -> (reuse) e1
//  X  [64K,80K): x tile -> (reuse) L3out + zf
// ---------------------------------------------------------------------------
__global__ __launch_bounds__(256, 2) void k1_mfma(
    const float* __restrict__ x, const unsigned short* __restrict__ wpack,
    const float* __restrict__ b0, const float* __restrict__ b1,
    const float* __restrict__ b2, const float* __restrict__ b3,
    const float* __restrict__ eb0, const float* __restrict__ eb1,
    const float* __restrict__ eb2,
    float* __restrict__ zg, float* __restrict__ gamma)
{
  __shared__ char sm[81920];
  char* H1  = sm;                   // 32 KB, rows 512B
  char* H2  = sm + 32768;           // 32 KB, rows 512B
  char* X   = sm + 65536;           // 16 KB, rows 256B
  char* L3o = sm + 65536;           // 8 KB, rows 128B (after X dead)
  float* zf = (float*)(sm + 73728); // fp32 [64][8]
  char* E0o = sm;                   // 16 KB, rows 256B (after H1 dead)
  char* e1  = sm + 32768;           // 8 KB, rows 128B (after H2 dead)

  const int tid = threadIdx.x;
  const int lane = tid & 63, wv = tid >> 6;
  const int l15 = lane & 15, lg = lane >> 4;
  const int sw = (l15 & 7) << 4;
  const int blk = blockIdx.x;

  // ---- stage x -> X: bf16 [64][128], swizzled ----
  {
    const float* xb = x + (size_t)blk * (TMS * 128);
#pragma unroll
    for (int p = 0; p < 8; ++p) {
      const int v = tid + p * 256;
      const float4 t = *(const float4*)(xb + v * 4);
      const int s = v >> 5, k0 = (v & 31) * 4;
      bf16x4 h = {(__bf16)t.x, (__bf16)t.y, (__bf16)t.z, (__bf16)t.w};
      *(bf16x4*)(X + s * 256 + ((k0 * 2) ^ ((s & 7) << 4))) = h;
    }
  }

  // L2 persistent accumulators, bias-initialized
  f32x4 acc2[4][4];
#pragma unroll
  for (int t = 0; t < 4; ++t) {
    const float4 bv = *(const float4*)(b1 + (wv * 4 + t) * 16 + lg * 4);
#pragma unroll
    for (int sg = 0; sg < 4; ++sg) acc2[t][sg] = {bv.x, bv.y, bv.z, bv.w};
  }
  __syncthreads();

  layer_nks4<4>(X, 256, H1, 512, wpack, 0, b0, lane, wv);         // L1 n 0..255
  __syncthreads();
  l2_accum<2>(H1, wpack, 0, acc2, lane, wv);                      // L2 k 0..255
  __syncthreads();
  layer_nks4<4>(X, 256, H1, 512, wpack, 64, b0 + 256, lane, wv);  // L1 n 256..511
  __syncthreads();
  l2_accum<2>(H1, wpack, 8, acc2, lane, wv);                      // L2 k 256..511

  // L2 epilogue -> H2
#pragma unroll
  for (int t = 0; t < 4; ++t)
#pragma unroll
    for (int sg = 0; sg < 4; ++sg) {
      bf16x4 tv;
#pragma unroll
      for (int r = 0; r < 4; ++r) tv[r] = (__bf16)fast_tanh(acc2[t][sg][r]);
      *(bf16x4*)(H2 + (sg * 16 + l15) * 512 + (((wv * 4 + t) * 32 + lg * 8) ^ sw)) = tv;
    }
  __syncthreads();

  // ---- L3: 256 -> 64 tanh; nt = wv ----
  {
    f32x4 acc[4];
    const float4 bv = *(const float4*)(b2 + wv * 16 + lg * 4);
#pragma unroll
    for (int sg = 0; sg < 4; ++sg) acc[sg] = {bv.x, bv.y, bv.z, bv.w};
#pragma unroll
    for (int ch = 0; ch < 2; ++ch) {
      bf16x8 a[4][4];
#pragma unroll
      for (int sg = 0; sg < 4; ++sg)
#pragma unroll
        for (int q = 0; q < 4; ++q)
          a[sg][q] = *(const bf16x8*)(H2 + (sg * 16 + l15) * 512 + (((ch * 4 + q) * 64 + lg * 16) ^ sw));
#pragma unroll
      for (int q = 0; q < 4; ++q) {
        const bf16x8 w = *(const bf16x8*)(wpack + ((size_t)(384 + wv * 8 + ch * 4 + q) * 64 + lane) * 8);
#pragma unroll
        for (int sg = 0; sg < 4; ++sg)
          acc[sg] = __builtin_amdgcn_mfma_f32_16x16x32_bf16(w, a[sg][q], acc[sg], 0, 0, 0);
      }
    }
#pragma unroll
    for (int sg = 0; sg < 4; ++sg) {
      bf16x4 tv;
#pragma unroll
      for (int r = 0; r < 4; ++r) tv[r] = (__bf16)fast_tanh(acc[sg][r]);
      *(bf16x4*)(L3o + (sg * 16 + l15) * 128 + ((wv * 32 + lg * 8) ^ sw)) = tv;
    }
  }
  __syncthreads();

  // ---- L4: 64 -> 8 (N padded 16); sample group = wv ----
  {
    bf16x8 a[2];
#pragma unroll
    for (int q = 0; q < 2; ++q)
      a[q] = *(const bf16x8*)(L3o + (wv * 16 + l15) * 128 + ((q * 64 + lg * 16) ^ sw));
    float4 bv = {0.f, 0.f, 0.f, 0.f};
    if (lg < 2) bv = *(const float4*)(b3 + lg * 4);
    f32x4 acc = {bv.x, bv.y, bv.z, bv.w};
#pragma unroll
    for (int q = 0; q < 2; ++q) {
      const bf16x8 w = *(const bf16x8*)(wpack + ((size_t)(440 + q) * 64 + lane) * 8);
      acc = __builtin_amdgcn_mfma_f32_16x16x32_bf16(w, a[q], acc, 0, 0, 0);
    }
    if (lg < 2) {
      *(f32x4*)(zf + (wv * 16 + l15) * 8 + lg * 4) = acc;
      *(f32x4*)(zg + ((size_t)blk * 64 + wv * 16 + l15) * 8 + lg * 4) = acc;
    }
  }
  __syncthreads();

  // ---- E0: 8 -> 128 tanh (K padded to 32, zero weights kill k>=8) ----
  {
    bf16x8 az[4];
#pragma unroll
    for (int sg = 0; sg < 4; ++sg) {
      const float* zr = zf + (sg * 16 + l15) * 8;
      const float4 p0 = *(const float4*)zr, p1 = *(const float4*)(zr + 4);
      az[sg] = {(__bf16)p0.x, (__bf16)p0.y, (__bf16)p0.z, (__bf16)p0.w,
                (__bf16)p1.x, (__bf16)p1.y, (__bf16)p1.z, (__bf16)p1.w};
    }
#pragma unroll
    for (int t = 0; t < 2; ++t) {
      const int nt = wv * 2 + t;
      const float4 bv = *(const float4*)(eb0 + nt * 16 + lg * 4);
      const bf16x8 w = *(const bf16x8*)(wpack + ((size_t)(432 + nt) * 64 + lane) * 8);
#pragma unroll
      for (int sg = 0; sg < 4; ++sg) {
        f32x4 acc = {bv.x, bv.y, bv.z, bv.w};
        acc = __builtin_amdgcn_mfma_f32_16x16x32_bf16(w, az[sg], acc, 0, 0, 0);
        bf16x4 tv;
#pragma unroll
        for (int r = 0; r < 4; ++r) tv[r] = (__bf16)fast_tanh(acc[r]);
        *(bf16x4*)(E0o + (sg * 16 + l15) * 256 + ((nt * 32 + lg * 8) ^ sw)) = tv;
      }
    }
  }
  __syncthreads();

  layer_nks4<1>(E0o, 256, e1, 128, wpack, 416, eb1, lane, wv);    // E1
  __syncthreads();

  // ---- E2 + softmax; sample group = wv ----
  {
    bf16x8 a[2];
#pragma unroll
    for (int q = 0; q < 2; ++q)
      a[q] = *(const bf16x8*)(e1 + (wv * 16 + l15) * 128 + ((q * 64 + lg * 16) ^ sw));
    const float4 bv = *(const float4*)(eb2 + lg * 4);
    f32x4 acc = {bv.x, bv.y, bv.z, bv.w};
#pragma unroll
    for (int q = 0; q < 2; ++q) {
      const bf16x8 w = *(const bf16x8*)(wpack + ((size_t)(442 + q) * 64 + lane) * 8);
      acc = __builtin_amdgcn_mfma_f32_16x16x32_bf16(w, a[q], acc, 0, 0, 0);
    }
    float m = fmaxf(fmaxf(acc[0], acc[1]), fmaxf(acc[2], acc[3]));
    m = fmaxf(m, __shfl_xor(m, 16));
    m = fmaxf(m, __shfl_xor(m, 32));
    float e0v = __expf(acc[0] - m), e1v = __expf(acc[1] - m);
    float e2v = __expf(acc[2] - m), e3v = __expf(acc[3] - m);
    float s = e0v + e1v + e2v + e3v;
    s += __shfl_xor(s, 16);
    s += __shfl_xor(s, 32);
    const float inv = 1.0f / s;
    float4 g = {e0v * inv, e1v * inv, e2v * inv, e3v * inv};
    *(float4*)(gamma + ((size_t)blk * 64 + wv * 16 + l15) * 16 + lg * 4) = g;
  }
}

// ---------------------------------------------------------------------------
// K2a: moment partials. 1024 blocks x 256 samples each, LDS-staged.
// ---------------------------------------------------------------------------
__global__ __launch_bounds__(256) void k2a_partial(
    const float* __restrict__ zg, const float* __restrict__ gamma,
    float* __restrict__ part)
{
  __shared__ float zl[256 * 8];
  __shared__ float gl[256 * 16];
  __shared__ float red[4][16][46];
  const int tid = threadIdx.x;
  const int blk = blockIdx.x;
  const int s0 = blk * 256;

  {
    const float4 a = *(const float4*)(zg + (size_t)(s0 + tid) * 8);
    const float4 b = *(const float4*)(zg + (size_t)(s0 + tid) * 8 + 4);
    *(float4*)(&zl[tid * 8])     = a;
    *(float4*)(&zl[tid * 8 + 4]) = b;
  }
  {
    const float* gp = gamma + (size_t)(s0 + tid) * 16;
#pragma unroll
    for (int q = 0; q < 4; ++q)
      *(float4*)(&gl[tid * 16 + q * 4]) = *(const float4*)(gp + q * 4);
  }
  __syncthreads();

  const int k = tid & 15, sub = tid >> 4;
  float m2[36], m1[8], gs = 0.f;
#pragma unroll
  for (int i = 0; i < 36; ++i) m2[i] = 0.f;
#pragma unroll
  for (int i = 0; i < 8; ++i) m1[i] = 0.f;

#pragma unroll 4
  for (int i = 0; i < 16; ++i) {
    const int n = i * 16 + sub;
    const float4 za = *(const float4*)(&zl[n * 8]);
    const float4 zb = *(const float4*)(&zl[n * 8 + 4]);
    const float zv[8] = {za.x, za.y, za.z, za.w, zb.x, zb.y, zb.z, zb.w};
    const float g = gl[n * 16 + k];
    gs += g;
    float t[8];
#pragma unroll
    for (int l = 0; l < 8; ++l) { t[l] = g * zv[l]; m1[l] += t[l]; }
    int p = 0;
#pragma unroll
    for (int l = 0; l < 8; ++l)
#pragma unroll
      for (int m = l; m < 8; ++m) {
        m2[p] = fmaf(t[l], zv[m], m2[p]);
        ++p;
      }
  }

#pragma unroll
  for (int i = 0; i < 36; ++i) {
    m2[i] += __shfl_xor(m2[i], 16);
    m2[i] += __shfl_xor(m2[i], 32);
  }
#pragma unroll
  for (int i = 0; i < 8; ++i) {
    m1[i] += __shfl_xor(m1[i], 16);
    m1[i] += __shfl_xor(m1[i], 32);
  }
  gs += __shfl_xor(gs, 16);
  gs += __shfl_xor(gs, 32);

  const int lane = tid & 63, wv = tid >> 6;
  if (lane < 16) {
#pragma unroll
    for (int i = 0; i < 36; ++i) red[wv][lane][i] = m2[i];
#pragma unroll
    for (int i = 0; i < 8; ++i) red[wv][lane][36 + i] = m1[i];
    red[wv][lane][44] = gs;
  }
  __syncthreads();

  for (int o = tid; o < 768; o += 256) {
    const int kk = o / 48, p = o % 48;
    float v = 0.f;
    if (p < 45)
      v = red[0][kk][p] + red[1][kk][p] + red[2][kk][p] + red[3][kk][p];
    part[(size_t)blk * 768 + o] = v;
  }
}

// ---------------------------------------------------------------------------
// K2b: reduce part[1024][768] -> stats[768]. 24 blocks.
// ---------------------------------------------------------------------------
__global__ __launch_bounds__(256) void k2b_reduce(
    const float* __restrict__ part, float* __restrict__ stats)
{
  const int oi = blockIdx.x % 3, jc = blockIdx.x / 3;
  const int o = oi * 256 + threadIdx.x;
  float s = 0.f;
#pragma unroll 4
  for (int j = jc * 128; j < jc * 128 + 128; ++j)
    s += part[(size_t)j * 768 + o];
  atomicAdd(&stats[o], s);
}

// ---------------------------------------------------------------------------
// K3: finalize GMM params -> quadratic coefficients (stats stride 48)
// ---------------------------------------------------------------------------
__global__ void k3_finalize(const float* __restrict__ stats, float* __restrict__ coef)
{
  const int k = threadIdx.x;
  if (k >= 16) return;
  const float* sk = stats + k * 48;
  const float gs = sk[44];
  float mu[8];
#pragma unroll
  for (int l = 0; l < 8; ++l) mu[l] = sk[36 + l] / gs;

  float S[8][8];
  {
    int p = 0;
    for (int l = 0; l < 8; ++l)
      for (int m = l; m < 8; ++m) {
        const float v = sk[p++] / gs - mu[l] * mu[m];
        S[l][m] = v; S[m][l] = v;
      }
  }
  for (int l = 0; l < 8; ++l) S[l][l] += 1e-6f;

  float L[8][8];
  for (int i = 0; i < 8; ++i)
    for (int j = 0; j <= i; ++j) {
      float s = S[i][j];
      for (int t = 0; t < j; ++t) s -= L[i][t] * L[j][t];
      if (i == j) L[i][i] = sqrtf(s);
      else        L[i][j] = s / L[j][j];
    }
  float logdet = 0.f;
  for (int i = 0; i < 8; ++i) logdet += logf(L[i][i]);
  logdet *= 2.f;

  float U[8][8];
  for (int j = 0; j < 8; ++j) {
    U[j][j] = 1.f / L[j][j];
    for (int i = j + 1; i < 8; ++i) {
      float s = 0.f;
      for (int t = j; t < i; ++t) s += L[i][t] * U[t][j];
      U[i][j] = -s / L[i][i];
    }
  }
  float Amat[8][8];
  for (int l = 0; l < 8; ++l)
    for (int m = l; m < 8; ++m) {
      float s = 0.f;
      for (int i = m; i < 8; ++i) s += U[i][l] * U[i][m];
      Amat[l][m] = s; Amat[m][l] = s;
    }
  float c[8];
  for (int l = 0; l < 8; ++l) {
    float s = 0.f;
    for (int m = 0; m < 8; ++m) s += Amat[l][m] * mu[m];
    c[l] = s;
  }
  float muAmu = 0.f;
  for (int l = 0; l < 8; ++l) muAmu += c[l] * mu[l];

  const float LOG2PI = 1.8378770664093453f;
  const float cnst = logf(gs) - logf((float)NSAMP)
                   - 0.5f * (8.f * LOG2PI + logdet + muAmu);

  float* ck = coef + k * 48;
  {
    int p = 0;
    for (int l = 0; l < 8; ++l)
      for (int m = l; m < 8; ++m) {
        ck[p] = (l == m) ? (-0.5f * Amat[l][l]) : (-Amat[l][m]);
        ++p;
      }
  }
  for (int l = 0; l < 8; ++l) ck[36 + l] = c[l];
  ck[44] = cnst;
  ck[45] = 0.f; ck[46] = 0.f; ck[47] = 0.f;
}

// ---------------------------------------------------------------------------
// K4: per-sample energy + online LSE
// ---------------------------------------------------------------------------
__global__ __launch_bounds__(256) void k4_energy(
    const float* __restrict__ zg, const float* __restrict__ coef,
    float* __restrict__ prob)
{
  __shared__ float C[16 * 48];
  for (int i = threadIdx.x; i < 16 * 48; i += 256) C[i] = coef[i];
  __syncthreads();

  const int n = blockIdx.x * 256 + threadIdx.x;
  const float4 za = *(const float4*)(zg + (size_t)n * 8);
  const float4 zb = *(const float4*)(zg + (size_t)n * 8 + 4);
  const float z[8] = {za.x, za.y, za.z, za.w, zb.x, zb.y, zb.z, zb.w};

  float pr[36];
  {
    int p = 0;
#pragma unroll
    for (int l = 0; l < 8; ++l)
#pragma unroll
      for (int m = l; m < 8; ++m) pr[p++] = z[l] * z[m];
  }

  float mx = -1e30f, sm = 0.f;
#pragma unroll
  for (int k = 0; k < 16; ++k) {
    const float4* c4 = (const float4*)&C[k * 48];
    float acc = C[k * 48 + 44];
#pragma unroll
    for (int q = 0; q < 9; ++q) {
      const float4 t = c4[q];
      acc = fmaf(t.x, pr[q * 4 + 0], acc);
      acc = fmaf(t.y, pr[q * 4 + 1], acc);
      acc = fmaf(t.z, pr[q * 4 + 2], acc);
      acc = fmaf(t.w, pr[q * 4 + 3], acc);
    }
    {
      const float4 t = c4[9];
      acc = fmaf(t.x, z[0], acc); acc = fmaf(t.y, z[1], acc);
      acc = fmaf(t.z, z[2], acc); acc = fmaf(t.w, z[3], acc);
    }
    {
      const float4 t = c4[10];
      acc = fmaf(t.x, z[4], acc); acc = fmaf(t.y, z[5], acc);
      acc = fmaf(t.z, z[6], acc); acc = fmaf(t.w, z[7], acc);
    }
    const float nm = fmaxf(mx, acc);
    sm = sm * __expf(mx - nm) + __expf(acc - nm);
    mx = nm;
  }
  prob[n] = -(mx + __logf(sm));
}

// ---------------------------------------------------------------------------
extern "C" void kernel_launch(void* const* d_in, const int* in_sizes, int n_in,
                              void* d_out, int out_size, void* d_ws, size_t ws_size,
                              hipStream_t stream)
{
  const float* x   = (const float*)d_in[0];
  const float* W0  = (const float*)d_in[1];
  const float* b0  = (const float*)d_in[2];
  const float* W1  = (const float*)d_in[3];
  const float* b1  = (const float*)d_in[4];
  const float* W2  = (const float*)d_in[5];
  const float* b2  = (const float*)d_in[6];
  const float* W3  = (const float*)d_in[7];
  const float* b3  = (const float*)d_in[8];
  const float* E0w = (const float*)d_in[9];
  const float* eb0 = (const float*)d_in[10];
  const float* E1w = (const float*)d_in[11];
  const float* eb1 = (const float*)d_in[12];
  const float* E2w = (const float*)d_in[13];
  const float* eb2 = (const float*)d_in[14];

  float* out  = (float*)d_out;
  float* prob = out;              // [N]
  float* zg   = out + NSAMP;      // [N][8]

  // ws: wpack (444 frags * 512 B, padded to 448 KB) | gamma [N][16]
  //   | stats 768 | coef 768 | part [1024][768]
  unsigned short* wpack = (unsigned short*)d_ws;
  float* ws    = (float*)d_ws;
  float* gamma = ws + 114688;
  float* stats = gamma + (size_t)NSAMP * 16;
  float* coef  = stats + 768;
  float* part  = coef + 768;

  hipMemsetAsync(stats, 0, 768 * sizeof(float), stream);

  k0_pack<<<444, 64, 0, stream>>>(W0, W1, W2, E1w, E0w, W3, E2w, wpack);
  k1_mfma<<<NSAMP / TMS, 256, 0, stream>>>(x, wpack, b0, b1, b2, b3,
                                           eb0, eb1, eb2, zg, gamma);
  k2a_partial<<<1024, 256, 0, stream>>>(zg, gamma, part);
  k2b_reduce<<<24, 256, 0, stream>>>(part, stats);
  k3_finalize<<<1, 64, 0, stream>>>(stats, coef);
  k4_energy<<<NSAMP / 256, 256, 0, stream>>>(zg, coef, prob);
}

// Round 9
// 204.530 us; speedup vs baseline: 11.4477x; 1.2890x over previous
//
#include <hip/hip_runtime.h>
#include <math.h>

#define NSAMP 262144
#define TMS 64   // samples per block in k1

typedef __bf16  bf16x8 __attribute__((ext_vector_type(8)));
typedef __bf16  bf16x4 __attribute__((ext_vector_type(4)));
typedef float   f32x4  __attribute__((ext_vector_type(4)));

// tanh via native exp + native rcp (1-ulp): avoids the ~10-inst correctly-
// rounded f32 division sequence the compiler must otherwise emit (no fast-math).
__device__ __forceinline__ float fast_tanh(float v) {
  float e = __expf(2.0f * v);
  return 1.0f - 2.0f * __builtin_amdgcn_rcpf(e + 1.0f);
}
__device__ __forceinline__ unsigned short f2bf(float f) {
  unsigned u = __float_as_uint(f);
  unsigned r = (u + 0x7FFFu + ((u >> 16) & 1u)) >> 16;   // RNE
  return (unsigned short)r;
}

// ---------------------------------------------------------------------------
// K0: pack all weights into bf16 MFMA *A-operand* fragments of W^T:
// lane l holds W[k = ks*32+(l>>4)*8+i][n = nt*16+(l&15)], zero-padded OOB.
// sections: L1 [0,128) NKS=4 N=512 | L2 [128,384) NKS=16 N=256
//   L3 [384,416) NKS=8 N=64 | E1 [416,432) NKS=4 N=64
//   E0 [432,440) NKS=1 N=128 K=8 | L4 [440,442) NKS=2 N=8->16 K=64
//   E2 [442,444) NKS=2 N=16 K=64
// ---------------------------------------------------------------------------
__global__ void k0_pack(const float* __restrict__ W0, const float* __restrict__ W1,
                        const float* __restrict__ W2, const float* __restrict__ E1w,
                        const float* __restrict__ E0w, const float* __restrict__ W3,
                        const float* __restrict__ E2w,
                        unsigned short* __restrict__ wpack)
{
  const int f = blockIdx.x;
  const int lane = threadIdx.x;
  const float* W; int NKS, N, Kreal, Nreal, local;
  if (f < 128)      { W = W0;  NKS = 4;  N = 512; Kreal = 128; Nreal = 512; local = f; }
  else if (f < 384) { W = W1;  NKS = 16; N = 256; Kreal = 512; Nreal = 256; local = f - 128; }
  else if (f < 416) { W = W2;  NKS = 8;  N = 64;  Kreal = 256; Nreal = 64;  local = f - 384; }
  else if (f < 432) { W = E1w; NKS = 4;  N = 64;  Kreal = 128; Nreal = 64;  local = f - 416; }
  else if (f < 440) { W = E0w; NKS = 1;  N = 128; Kreal = 8;   Nreal = 128; local = f - 432; }
  else if (f < 442) { W = W3;  NKS = 2;  N = 8;   Kreal = 64;  Nreal = 8;   local = f - 440; }
  else              { W = E2w; NKS = 2;  N = 16;  Kreal = 64;  Nreal = 16;  local = f - 442; }
  const int nt = local / NKS, ks = local % NKS;
  const int n = nt * 16 + (lane & 15);
  const int kbase = ks * 32 + (lane >> 4) * 8;
  unsigned short* out = wpack + ((size_t)f * 64 + lane) * 8;
#pragma unroll
  for (int i = 0; i < 8; ++i) {
    const int k = kbase + i;
    const float v = (k < Kreal && n < Nreal) ? W[(size_t)k * N + n] : 0.f;
    out[i] = f2bf(v);
  }
}

// ---------------------------------------------------------------------------
// Swapped-operand layer, NKS=4 (a-frags cached across tiles), 4 sample groups.
// ---------------------------------------------------------------------------
template<int NTPW>
__device__ __forceinline__ void layer_nks4(
    const char* __restrict__ in, int inRowB, char* __restrict__ outb, int outRowB,
    const unsigned short* __restrict__ wp, int fragBase,
    const float* __restrict__ bias, int lane, int wv)
{
  const int l15 = lane & 15, lg = lane >> 4;
  const int sw = (l15 & 7) << 4;
  bf16x8 a[4][4];
#pragma unroll
  for (int sg = 0; sg < 4; ++sg)
#pragma unroll
    for (int q = 0; q < 4; ++q)
      a[sg][q] = *(const bf16x8*)(in + (sg * 16 + l15) * inRowB + ((q * 64 + lg * 16) ^ sw));
#pragma unroll
  for (int t = 0; t < NTPW; ++t) {
    const int nt = wv * NTPW + t;
    const float4 bv = *(const float4*)(bias + nt * 16 + lg * 4);
    f32x4 acc[4];
#pragma unroll
    for (int sg = 0; sg < 4; ++sg) acc[sg] = {bv.x, bv.y, bv.z, bv.w};
#pragma unroll
    for (int q = 0; q < 4; ++q) {
      const bf16x8 w = *(const bf16x8*)(wp + ((size_t)(fragBase + nt * 4 + q) * 64 + lane) * 8);
#pragma unroll
      for (int sg = 0; sg < 4; ++sg)
        acc[sg] = __builtin_amdgcn_mfma_f32_16x16x32_bf16(w, a[sg][q], acc[sg], 0, 0, 0);
    }
#pragma unroll
    for (int sg = 0; sg < 4; ++sg) {
      bf16x4 tv;
#pragma unroll
      for (int r = 0; r < 4; ++r) tv[r] = (__bf16)fast_tanh(acc[sg][r]);
      *(bf16x4*)(outb + (sg * 16 + l15) * outRowB + ((nt * 32 + lg * 8) ^ sw)) = tv;
    }
  }
}

// ---------------------------------------------------------------------------
// L2 partial accumulation: K-half of 256 (2 chunks x 4 kfrags) into persistent
// acc[4 tiles][4 sg]. H1 rows 512B hold the current L1 half (relative k).
// ---------------------------------------------------------------------------
template<int NCH>
__device__ __forceinline__ void l2_accum(
    const char* __restrict__ H1, const unsigned short* __restrict__ wp,
    int ksOff, f32x4 (&acc)[4][4], int lane, int wv)
{
  const int l15 = lane & 15, lg = lane >> 4;
  const int sw = (l15 & 7) << 4;
#pragma unroll
  for (int ch = 0; ch < NCH; ++ch) {
    bf16x8 a[4][4];
#pragma unroll
    for (int sg = 0; sg < 4; ++sg)
#pragma unroll
      for (int q = 0; q < 4; ++q)
        a[sg][q] = *(const bf16x8*)(H1 + (sg * 16 + l15) * 512 + (((ch * 4 + q) * 64 + lg * 16) ^ sw));
#pragma unroll
    for (int t = 0; t < 4; ++t) {
      const int nt = wv * 4 + t;
#pragma unroll
      for (int q = 0; q < 4; ++q) {
        const bf16x8 w = *(const bf16x8*)(wp + ((size_t)(128 + nt * 16 + ksOff + ch * 4 + q) * 64 + lane) * 8);
#pragma unroll
        for (int sg = 0; sg < 4; ++sg)
          acc[t][sg] = __builtin_amdgcn_mfma_f32_16x16x32_bf16(w, a[sg][q], acc[t][sg], 0, 0, 0);
      }
    }
  }
}

// ---------------------------------------------------------------------------
// K1: fused MLP, TMS=64, half-pass L1/L2. LDS 80 KB -> 2 blocks/CU.
//  H1 [0,32K): L1out half -> (reuse) E0out
//  H2 [32K,64K): L2out -> (reuse) e1
//  X  [64K,80K): x tile -> (reuse) L3out + z-bf16
// ---------------------------------------------------------------------------
__global__ __launch_bounds__(256, 2) void k1_mfma(
    const float* __restrict__ x, const unsigned short* __restrict__ wpack,
    const float* __restrict__ b0, const float* __restrict__ b1,
    const float* __restrict__ b2, const float* __restrict__ b3,
    const float* __restrict__ eb0, const float* __restrict__ eb1,
    const float* __restrict__ eb2,
    float* __restrict__ zg, float* __restrict__ gamma)
{
  __shared__ char sm[81920];
  char* H1  = sm;                   // 32 KB, rows 512B
  char* H2  = sm + 32768;           // 32 KB, rows 512B
  char* X   = sm + 65536;           // 16 KB, rows 256B
  char* L3o = sm + 65536;           // 8 KB, rows 128B (after X dead)
  char* zb  = sm + 73728;           // 1 KB: z bf16 [64][8], rows 16B
  char* E0o = sm;                   // 16 KB, rows 256B (after H1 dead)
  char* e1  = sm + 32768;           // 8 KB, rows 128B (after H2 dead)

  const int tid = threadIdx.x;
  const int lane = tid & 63, wv = tid >> 6;
  const int l15 = lane & 15, lg = lane >> 4;
  const int sw = (l15 & 7) << 4;
  const int blk = blockIdx.x;

  // ---- stage x -> X: bf16 [64][128], swizzled ----
  {
    const float* xb = x + (size_t)blk * (TMS * 128);
#pragma unroll
    for (int p = 0; p < 8; ++p) {
      const int v = tid + p * 256;
      const float4 t = *(const float4*)(xb + v * 4);
      const int s = v >> 5, k0 = (v & 31) * 4;
      bf16x4 h = {(__bf16)t.x, (__bf16)t.y, (__bf16)t.z, (__bf16)t.w};
      *(bf16x4*)(X + s * 256 + ((k0 * 2) ^ ((s & 7) << 4))) = h;
    }
  }

  // L2 persistent accumulators, bias-initialized
  f32x4 acc2[4][4];
#pragma unroll
  for (int t = 0; t < 4; ++t) {
    const float4 bv = *(const float4*)(b1 + (wv * 4 + t) * 16 + lg * 4);
#pragma unroll
    for (int sg = 0; sg < 4; ++sg) acc2[t][sg] = {bv.x, bv.y, bv.z, bv.w};
  }
  __syncthreads();

  layer_nks4<4>(X, 256, H1, 512, wpack, 0, b0, lane, wv);         // L1 n 0..255
  __syncthreads();
  l2_accum<2>(H1, wpack, 0, acc2, lane, wv);                      // L2 k 0..255
  __syncthreads();
  layer_nks4<4>(X, 256, H1, 512, wpack, 64, b0 + 256, lane, wv);  // L1 n 256..511
  __syncthreads();
  l2_accum<2>(H1, wpack, 8, acc2, lane, wv);                      // L2 k 256..511

  // L2 epilogue -> H2
#pragma unroll
  for (int t = 0; t < 4; ++t)
#pragma unroll
    for (int sg = 0; sg < 4; ++sg) {
      bf16x4 tv;
#pragma unroll
      for (int r = 0; r < 4; ++r) tv[r] = (__bf16)fast_tanh(acc2[t][sg][r]);
      *(bf16x4*)(H2 + (sg * 16 + l15) * 512 + (((wv * 4 + t) * 32 + lg * 8) ^ sw)) = tv;
    }
  __syncthreads();

  // ---- L3: 256 -> 64 tanh; nt = wv ----
  {
    f32x4 acc[4];
    const float4 bv = *(const float4*)(b2 + wv * 16 + lg * 4);
#pragma unroll
    for (int sg = 0; sg < 4; ++sg) acc[sg] = {bv.x, bv.y, bv.z, bv.w};
#pragma unroll
    for (int ch = 0; ch < 2; ++ch) {
      bf16x8 a[4][4];
#pragma unroll
      for (int sg = 0; sg < 4; ++sg)
#pragma unroll
        for (int q = 0; q < 4; ++q)
          a[sg][q] = *(const bf16x8*)(H2 + (sg * 16 + l15) * 512 + (((ch * 4 + q) * 64 + lg * 16) ^ sw));
#pragma unroll
      for (int q = 0; q < 4; ++q) {
        const bf16x8 w = *(const bf16x8*)(wpack + ((size_t)(384 + wv * 8 + ch * 4 + q) * 64 + lane) * 8);
#pragma unroll
        for (int sg = 0; sg < 4; ++sg)
          acc[sg] = __builtin_amdgcn_mfma_f32_16x16x32_bf16(w, a[sg][q], acc[sg], 0, 0, 0);
      }
    }
#pragma unroll
    for (int sg = 0; sg < 4; ++sg) {
      bf16x4 tv;
#pragma unroll
      for (int r = 0; r < 4; ++r) tv[r] = (__bf16)fast_tanh(acc[sg][r]);
      *(bf16x4*)(L3o + (sg * 16 + l15) * 128 + ((wv * 32 + lg * 8) ^ sw)) = tv;
    }
  }
  __syncthreads();

  // ---- L4: 64 -> 8 (N padded 16); sample group = wv.
  // z written fp32 to global (output) and bf16 to LDS (E0 operand). ----
  {
    bf16x8 a[2];
#pragma unroll
    for (int q = 0; q < 2; ++q)
      a[q] = *(const bf16x8*)(L3o + (wv * 16 + l15) * 128 + ((q * 64 + lg * 16) ^ sw));
    float4 bv = {0.f, 0.f, 0.f, 0.f};
    if (lg < 2) bv = *(const float4*)(b3 + lg * 4);
    f32x4 acc = {bv.x, bv.y, bv.z, bv.w};
#pragma unroll
    for (int q = 0; q < 2; ++q) {
      const bf16x8 w = *(const bf16x8*)(wpack + ((size_t)(440 + q) * 64 + lane) * 8);
      acc = __builtin_amdgcn_mfma_f32_16x16x32_bf16(w, a[q], acc, 0, 0, 0);
    }
    if (lg < 2) {
      *(f32x4*)(zg + ((size_t)blk * 64 + wv * 16 + l15) * 8 + lg * 4) = acc;
      bf16x4 zv;
#pragma unroll
      for (int r = 0; r < 4; ++r) zv[r] = (__bf16)acc[r];
      *(bf16x4*)(zb + (wv * 16 + l15) * 16 + lg * 8) = zv;
    }
  }
  __syncthreads();

  // ---- E0: 8 -> 128 tanh (K padded to 32, zero weights kill k>=8).
  // z read as bf16x8 rows directly (broadcast across lg). ----
  {
    bf16x8 az[4];
#pragma unroll
    for (int sg = 0; sg < 4; ++sg)
      az[sg] = *(const bf16x8*)(zb + (sg * 16 + l15) * 16);
#pragma unroll
    for (int t = 0; t < 2; ++t) {
      const int nt = wv * 2 + t;
      const float4 bv = *(const float4*)(eb0 + nt * 16 + lg * 4);
      const bf16x8 w = *(const bf16x8*)(wpack + ((size_t)(432 + nt) * 64 + lane) * 8);
#pragma unroll
      for (int sg = 0; sg < 4; ++sg) {
        f32x4 acc = {bv.x, bv.y, bv.z, bv.w};
        acc = __builtin_amdgcn_mfma_f32_16x16x32_bf16(w, az[sg], acc, 0, 0, 0);
        bf16x4 tv;
#pragma unroll
        for (int r = 0; r < 4; ++r) tv[r] = (__bf16)fast_tanh(acc[r]);
        *(bf16x4*)(E0o + (sg * 16 + l15) * 256 + ((nt * 32 + lg * 8) ^ sw)) = tv;
      }
    }
  }
  __syncthreads();

  layer_nks4<1>(E0o, 256, e1, 128, wpack, 416, eb1, lane, wv);    // E1
  __syncthreads();

  // ---- E2 + softmax; sample group = wv ----
  {
    bf16x8 a[2];
#pragma unroll
    for (int q = 0; q < 2; ++q)
      a[q] = *(const bf16x8*)(e1 + (wv * 16 + l15) * 128 + ((q * 64 + lg * 16) ^ sw));
    const float4 bv = *(const float4*)(eb2 + lg * 4);
    f32x4 acc = {bv.x, bv.y, bv.z, bv.w};
#pragma unroll
    for (int q = 0; q < 2; ++q) {
      const bf16x8 w = *(const bf16x8*)(wpack + ((size_t)(442 + q) * 64 + lane) * 8);
      acc = __builtin_amdgcn_mfma_f32_16x16x32_bf16(w, a[q], acc, 0, 0, 0);
    }
    float m = fmaxf(fmaxf(acc[0], acc[1]), fmaxf(acc[2], acc[3]));
    m = fmaxf(m, __shfl_xor(m, 16));
    m = fmaxf(m, __shfl_xor(m, 32));
    float e0v = __expf(acc[0] - m), e1v = __expf(acc[1] - m);
    float e2v = __expf(acc[2] - m), e3v = __expf(acc[3] - m);
    float s = e0v + e1v + e2v + e3v;
    s += __shfl_xor(s, 16);
    s += __shfl_xor(s, 32);
    const float inv = __builtin_amdgcn_rcpf(s);
    float4 g = {e0v * inv, e1v * inv, e2v * inv, e3v * inv};
    *(float4*)(gamma + ((size_t)blk * 64 + wv * 16 + l15) * 16 + lg * 4) = g;
  }
}

// ---------------------------------------------------------------------------
// K2a: moment partials. 1024 blocks x 256 samples each, LDS-staged.
// ---------------------------------------------------------------------------
__global__ __launch_bounds__(256) void k2a_partial(
    const float* __restrict__ zg, const float* __restrict__ gamma,
    float* __restrict__ part)
{
  __shared__ float zl[256 * 8];
  __shared__ float gl[256 * 16];
  __shared__ float red[4][16][46];
  const int tid = threadIdx.x;
  const int blk = blockIdx.x;
  const int s0 = blk * 256;

  {
    const float4 a = *(const float4*)(zg + (size_t)(s0 + tid) * 8);
    const float4 b = *(const float4*)(zg + (size_t)(s0 + tid) * 8 + 4);
    *(float4*)(&zl[tid * 8])     = a;
    *(float4*)(&zl[tid * 8 + 4]) = b;
  }
  {
    const float* gp = gamma + (size_t)(s0 + tid) * 16;
#pragma unroll
    for (int q = 0; q < 4; ++q)
      *(float4*)(&gl[tid * 16 + q * 4]) = *(const float4*)(gp + q * 4);
  }
  __syncthreads();

  const int k = tid & 15, sub = tid >> 4;
  float m2[36], m1[8], gs = 0.f;
#pragma unroll
  for (int i = 0; i < 36; ++i) m2[i] = 0.f;
#pragma unroll
  for (int i = 0; i < 8; ++i) m1[i] = 0.f;

#pragma unroll 4
  for (int i = 0; i < 16; ++i) {
    const int n = i * 16 + sub;
    const float4 za = *(const float4*)(&zl[n * 8]);
    const float4 zb4 = *(const float4*)(&zl[n * 8 + 4]);
    const float zv[8] = {za.x, za.y, za.z, za.w, zb4.x, zb4.y, zb4.z, zb4.w};
    const float g = gl[n * 16 + k];
    gs += g;
    float t[8];
#pragma unroll
    for (int l = 0; l < 8; ++l) { t[l] = g * zv[l]; m1[l] += t[l]; }
    int p = 0;
#pragma unroll
    for (int l = 0; l < 8; ++l)
#pragma unroll
      for (int m = l; m < 8; ++m) {
        m2[p] = fmaf(t[l], zv[m], m2[p]);
        ++p;
      }
  }

#pragma unroll
  for (int i = 0; i < 36; ++i) {
    m2[i] += __shfl_xor(m2[i], 16);
    m2[i] += __shfl_xor(m2[i], 32);
  }
#pragma unroll
  for (int i = 0; i < 8; ++i) {
    m1[i] += __shfl_xor(m1[i], 16);
    m1[i] += __shfl_xor(m1[i], 32);
  }
  gs += __shfl_xor(gs, 16);
  gs += __shfl_xor(gs, 32);

  const int lane = tid & 63, wv = tid >> 6;
  if (lane < 16) {
#pragma unroll
    for (int i = 0; i < 36; ++i) red[wv][lane][i] = m2[i];
#pragma unroll
    for (int i = 0; i < 8; ++i) red[wv][lane][36 + i] = m1[i];
    red[wv][lane][44] = gs;
  }
  __syncthreads();

  for (int o = tid; o < 768; o += 256) {
    const int kk = o / 48, p = o % 48;
    float v = 0.f;
    if (p < 45)
      v = red[0][kk][p] + red[1][kk][p] + red[2][kk][p] + red[3][kk][p];
    part[(size_t)blk * 768 + o] = v;
  }
}

// ---------------------------------------------------------------------------
// K2b: reduce part[1024][768] -> stats[768]. 24 blocks.
// ---------------------------------------------------------------------------
__global__ __launch_bounds__(256) void k2b_reduce(
    const float* __restrict__ part, float* __restrict__ stats)
{
  const int oi = blockIdx.x % 3, jc = blockIdx.x / 3;
  const int o = oi * 256 + threadIdx.x;
  float s = 0.f;
#pragma unroll 4
  for (int j = jc * 128; j < jc * 128 + 128; ++j)
    s += part[(size_t)j * 768 + o];
  atomicAdd(&stats[o], s);
}

// ---------------------------------------------------------------------------
// K3: finalize GMM params -> quadratic coefficients (stats stride 48)
// ---------------------------------------------------------------------------
__global__ void k3_finalize(const float* __restrict__ stats, float* __restrict__ coef)
{
  const int k = threadIdx.x;
  if (k >= 16) return;
  const float* sk = stats + k * 48;
  const float gs = sk[44];
  float mu[8];
#pragma unroll
  for (int l = 0; l < 8; ++l) mu[l] = sk[36 + l] / gs;

  float S[8][8];
  {
    int p = 0;
    for (int l = 0; l < 8; ++l)
      for (int m = l; m < 8; ++m) {
        const float v = sk[p++] / gs - mu[l] * mu[m];
        S[l][m] = v; S[m][l] = v;
      }
  }
  for (int l = 0; l < 8; ++l) S[l][l] += 1e-6f;

  float L[8][8];
  for (int i = 0; i < 8; ++i)
    for (int j = 0; j <= i; ++j) {
      float s = S[i][j];
      for (int t = 0; t < j; ++t) s -= L[i][t] * L[j][t];
      if (i == j) L[i][i] = sqrtf(s);
      else        L[i][j] = s / L[j][j];
    }
  float logdet = 0.f;
  for (int i = 0; i < 8; ++i) logdet += logf(L[i][i]);
  logdet *= 2.f;

  float U[8][8];
  for (int j = 0; j < 8; ++j) {
    U[j][j] = 1.f / L[j][j];
    for (int i = j + 1; i < 8; ++i) {
      float s = 0.f;
      for (int t = j; t < i; ++t) s += L[i][t] * U[t][j];
      U[i][j] = -s / L[i][i];
    }
  }
  float Amat[8][8];
  for (int l = 0; l < 8; ++l)
    for (int m = l; m < 8; ++m) {
      float s = 0.f;
      for (int i = m; i < 8; ++i) s += U[i][l] * U[i][m];
      Amat[l][m] = s; Amat[m][l] = s;
    }
  float c[8];
  for (int l = 0; l < 8; ++l) {
    float s = 0.f;
    for (int m = 0; m < 8; ++m) s += Amat[l][m] * mu[m];
    c[l] = s;
  }
  float muAmu = 0.f;
  for (int l = 0; l < 8; ++l) muAmu += c[l] * mu[l];

  const float LOG2PI = 1.8378770664093453f;
  const float cnst = logf(gs) - logf((float)NSAMP)
                   - 0.5f * (8.f * LOG2PI + logdet + muAmu);

  float* ck = coef + k * 48;
  {
    int p = 0;
    for (int l = 0; l < 8; ++l)
      for (int m = l; m < 8; ++m) {
        ck[p] = (l == m) ? (-0.5f * Amat[l][l]) : (-Amat[l][m]);
        ++p;
      }
  }
  for (int l = 0; l < 8; ++l) ck[36 + l] = c[l];
  ck[44] = cnst;
  ck[45] = 0.f; ck[46] = 0.f; ck[47] = 0.f;
}

// ---------------------------------------------------------------------------
// K4: per-sample energy + online LSE
// ---------------------------------------------------------------------------
__global__ __launch_bounds__(256) void k4_energy(
    const float* __restrict__ zg, const float* __restrict__ coef,
    float* __restrict__ prob)
{
  __shared__ float C[16 * 48];
  for (int i = threadIdx.x; i < 16 * 48; i += 256) C[i] = coef[i];
  __syncthreads();

  const int n = blockIdx.x * 256 + threadIdx.x;
  const float4 za = *(const float4*)(zg + (size_t)n * 8);
  const float4 zb = *(const float4*)(zg + (size_t)n * 8 + 4);
  const float z[8] = {za.x, za.y, za.z, za.w, zb.x, zb.y, zb.z, zb.w};

  float pr[36];
  {
    int p = 0;
#pragma unroll
    for (int l = 0; l < 8; ++l)
#pragma unroll
      for (int m = l; m < 8; ++m) pr[p++] = z[l] * z[m];
  }

  float mx = -1e30f, sm = 0.f;
#pragma unroll
  for (int k = 0; k < 16; ++k) {
    const float4* c4 = (const float4*)&C[k * 48];
    float acc = C[k * 48 + 44];
#pragma unroll
    for (int q = 0; q < 9; ++q) {
      const float4 t = c4[q];
      acc = fmaf(t.x, pr[q * 4 + 0], acc);
      acc = fmaf(t.y, pr[q * 4 + 1], acc);
      acc = fmaf(t.z, pr[q * 4 + 2], acc);
      acc = fmaf(t.w, pr[q * 4 + 3], acc);
    }
    {
      const float4 t = c4[9];
      acc = fmaf(t.x, z[0], acc); acc = fmaf(t.y, z[1], acc);
      acc = fmaf(t.z, z[2], acc); acc = fmaf(t.w, z[3], acc);
    }
    {
      const float4 t = c4[10];
      acc = fmaf(t.x, z[4], acc); acc = fmaf(t.y, z[5], acc);
      acc = fmaf(t.z, z[6], acc); acc = fmaf(t.w, z[7], acc);
    }
    const float nm = fmaxf(mx, acc);
    sm = sm * __expf(mx - nm) + __expf(acc - nm);
    mx = nm;
  }
  prob[n] = -(mx + __logf(sm));
}

// ---------------------------------------------------------------------------
extern "C" void kernel_launch(void* const* d_in, const int* in_sizes, int n_in,
                              void* d_out, int out_size, void* d_ws, size_t ws_size,
                              hipStream_t stream)
{
  const float* x   = (const float*)d_in[0];
  const float* W0  = (const float*)d_in[1];
  const float* b0  = (const float*)d_in[2];
  const float* W1  = (const float*)d_in[3];
  const float* b1  = (const float*)d_in[4];
  const float* W2  = (const float*)d_in[5];
  const float* b2  = (const float*)d_in[6];
  const float* W3  = (const float*)d_in[7];
  const float* b3  = (const float*)d_in[8];
  const float* E0w = (const float*)d_in[9];
  const float* eb0 = (const float*)d_in[10];
  const float* E1w = (const float*)d_in[11];
  const float* eb1 = (const float*)d_in[12];
  const float* E2w = (const float*)d_in[13];
  const float* eb2 = (const float*)d_in[14];

  float* out  = (float*)d_out;
  float* prob = out;              // [N]
  float* zg   = out + NSAMP;      // [N][8]

  // ws: wpack (444 frags * 512 B, padded to 448 KB) | gamma [N][16]
  //   | stats 768 | coef 768 | part [1024][768]
  unsigned short* wpack = (unsigned short*)d_ws;
  float* ws    = (float*)d_ws;
  float* gamma = ws + 114688;
  float* stats = gamma + (size_t)NSAMP * 16;
  float* coef  = stats + 768;
  float* part  = coef + 768;

  hipMemsetAsync(stats, 0, 768 * sizeof(float), stream);

  k0_pack<<<444, 64, 0, stream>>>(W0, W1, W2, E1w, E0w, W3, E2w, wpack);
  k1_mfma<<<NSAMP / TMS, 256, 0, stream>>>(x, wpack, b0, b1, b2, b3,
                                           eb0, eb1, eb2, zg, gamma);
  k2a_partial<<<1024, 256, 0, stream>>>(zg, gamma, part);
  k2b_reduce<<<24, 256, 0, stream>>>(part, stats);
  k3_finalize<<<1, 64, 0, stream>>>(stats, coef);
  k4_energy<<<NSAMP / 256, 256, 0, stream>>>(zg, coef, prob);
}